// Round 13
// baseline (589.015 us; speedup 1.0000x reference)
//
#include <hip/hip_runtime.h>
#include <hip/hip_bf16.h>
#include <cstdint>
#include <cstddef>

// GuidedGNN: 3x GATConv(H=3, EMB=128, concat) + head transforms + MLP head.
// R11: CSR scans collapsed to one k_offsets dispatch (wave shfl-scan + global
// cursor atomicAdd; edge order becomes atomic-order dependent -- fp reorder
// noise only, well under threshold); k_fused stages half of B2 chunk-0 during
// stage-1's last K-step (sB[0] is dead there) hiding load latency.
// k_agg untouched (at gather-pattern floor: FETCH = 8 XCD x h exactly).

#define F_IN 128
#define EMB  128
#define NH   3
#define HE   (NH*EMB)   // 384
#define EXCAP 256       // per-wave LDS ex-cache entries (max real deg ~45)

typedef __attribute__((ext_vector_type(8))) short bf16x8;
typedef __attribute__((ext_vector_type(4))) float f32x4;

__device__ __forceinline__ float lrelu(float x){ return x > 0.f ? x : 0.2f * x; }
__device__ __forceinline__ float b2f(unsigned short u){ return __uint_as_float((unsigned)u << 16); }
__device__ __forceinline__ unsigned short f2b(float f){
  __hip_bfloat16 h = __float2bfloat16(f);
  return *reinterpret_cast<unsigned short*>(&h);
}
// channel permutation: orig c in [0,384) -> (c%128/2)*6 + head*2 + (c&1)
__device__ __forceinline__ int pi(int c){
  int hh = c >> 7, w = c & 127;
  return (w >> 1) * 6 + hh * 2 + (w & 1);
}
__device__ __forceinline__ void gload16(const unsigned short* g, unsigned short* l){
  __builtin_amdgcn_global_load_lds((const __attribute__((address_space(1))) unsigned int*)g,
                                   (__attribute__((address_space(3))) unsigned int*)l, 16, 0, 0);
}

struct u32x3 { unsigned x, y, z; };
struct f32x3 { float x, y, z; };

// ---------------- combined prep: x->bf16, weight transposes, cnt/cursor zero ----------------
#define S1 49152   // 128*384
#define S3 65536   // 128*512
__global__ void k_prep(const float* __restrict__ x, unsigned short* __restrict__ xb, int n4,
                       const float* __restrict__ W1, const float* __restrict__ W2,
                       const float* __restrict__ W3,
                       unsigned short* __restrict__ W1T, unsigned short* __restrict__ W2T,
                       unsigned short* __restrict__ W3T,
                       const float* __restrict__ Wh1, const float* __restrict__ Wh2,
                       const float* __restrict__ Wh3,
                       unsigned short* __restrict__ Wh1T, unsigned short* __restrict__ Wh2T,
                       unsigned short* __restrict__ Wh3T,
                       const float* __restrict__ Wl1, unsigned short* __restrict__ Wl1T,
                       int* __restrict__ cnt, int* __restrict__ cursor, int Nn){
  int i = blockIdx.x * 256 + threadIdx.x;
  if (i < n4){
    float4 v = reinterpret_cast<const float4*>(x)[i];
    unsigned short o[4] = {f2b(v.x), f2b(v.y), f2b(v.z), f2b(v.w)};
    *reinterpret_cast<uint2*>(&xb[i * 4]) = *reinterpret_cast<uint2*>(o);
    return;
  }
  i -= n4;
  if (i < 3 * S1){  // W1/W2/W3 [128,384] -> [384,128]
    const float* Wsrc = (i < S1) ? W1 : (i < 2 * S1) ? W2 : W3;
    unsigned short* Wdst = (i < S1) ? W1T : (i < 2 * S1) ? W2T : W3T;
    int j = i % S1;
    int r = j / HE, c = j % HE;
    Wdst[(size_t)c * F_IN + r] = f2b(Wsrc[j]);
    return;
  }
  i -= 3 * S1;
  if (i < 3 * S1){  // Wh1/2/3 [384,128] -> [128 cols][384] K pi-permuted
    const float* Wsrc = (i < S1) ? Wh1 : (i < 2 * S1) ? Wh2 : Wh3;
    unsigned short* Wdst = (i < S1) ? Wh1T : (i < 2 * S1) ? Wh2T : Wh3T;
    int j = i % S1;
    int r = j / F_IN, c = j % F_IN;
    Wdst[(size_t)c * HE + pi(r)] = f2b(Wsrc[j]);
    return;
  }
  i -= 3 * S1;
  if (i < S3){      // Wl1 [128,512] -> [512,128]
    int r = i / 512, c = i % 512;
    Wl1T[(size_t)c * F_IN + r] = f2b(Wl1[i]);
    return;
  }
  i -= S3;
  if (i < Nn){ cnt[i] = 0; return; }
  i -= Nn;
  if (i == 0) cursor[0] = 0;
}

// ---------------- CSR build (real edges only; self-loops handled in k_agg) ----------------
__global__ void k_hist(const int* __restrict__ ei, int E, int* __restrict__ cnt,
                       int* __restrict__ rank){
  for (int i = blockIdx.x * blockDim.x + threadIdx.x; i < E; i += gridDim.x * blockDim.x){
    int d = ei[E + i];
    rank[i] = atomicAdd(&cnt[d], 1);
  }
}

// one-dispatch offsets: wave shfl-scan + global cursor (replaces scan1/2/3).
// rs ranges are disjoint+exact; ordering across waves is atomic-order dependent
// (fp-sum reorder noise only, << absmax threshold).
__global__ void k_offsets(const int* __restrict__ cnt, int* __restrict__ rs,
                          int* __restrict__ cursor, int Nn){
  int n = blockIdx.x * 256 + threadIdx.x;
  int lane = threadIdx.x & 63;
  int v = (n < Nn) ? cnt[n] : 0;
  int inc = v;
#pragma unroll
  for (int off = 1; off < 64; off <<= 1){
    int t = __shfl_up(inc, off);
    if (lane >= off) inc += t;
  }
  int total = __shfl(inc, 63);
  int base = 0;
  if (lane == 0) base = atomicAdd(cursor, total);
  base = __shfl(base, 0);
  if (n < Nn) rs[n] = base + inc - v;
}

__global__ void k_scatter(const int* __restrict__ ei, int E, const int* __restrict__ rs,
                          const int* __restrict__ rank, int* __restrict__ esrc){
  for (int i = blockIdx.x * blockDim.x + threadIdx.x; i < E; i += gridDim.x * blockDim.x){
    esrc[rs[ei[E + i]] + rank[i]] = ei[i];
  }
}

// ---------------- LDS-pipelined MFMA GEMM (layer-1 only) ----------------
template<int K, bool PERM>
__global__ __launch_bounds__(256, 2) void k_mgemm(const unsigned short* __restrict__ A,
                                                  const unsigned short* __restrict__ BT,
                                                  const float* __restrict__ bias,
                                                  unsigned short* __restrict__ C,
                                                  const float* __restrict__ a_s,
                                                  const float* __restrict__ a_d,
                                                  float* __restrict__ als, float* __restrict__ ald,
                                                  int M, int Ncols, int act){
  __shared__ unsigned short sA[2][8192];   // [buf][128 rows x 64 k] swizzled
  __shared__ unsigned short sB[2][8192];
  const int lane = threadIdx.x & 63;
  const int wave = threadIdx.x >> 6;
  const int brow = blockIdx.x * 128;
  const int bcol = blockIdx.y * 128;
  const int wr = wave >> 1, wc = wave & 1;
  const int r15 = lane & 15;
  const int kg = (lane >> 4) * 8;
  const int row0 = brow + wr * 64;
  const int col0 = bcol + wc * 64;
  f32x4 acc[4][4] = {};

  const int cbase = wave * 64 + lane;
  auto stage = [&](int buf, int kt){
#pragma unroll
    for (int j = 0; j < 4; ++j){
      int c = cbase + j * 256;
      int r = c >> 3;
      int k0 = ((c ^ r) & 7) * 8;
      int ldsoff = (wave * 64 + j * 256) * 8;   // wave-uniform; HW adds lane*16B
      int ra = brow + r; if (ra >= M) ra = M - 1;
      gload16(&A[(size_t)ra * K + kt + k0], &sA[buf][ldsoff]);
      gload16(&BT[(size_t)(bcol + r) * K + kt + k0], &sB[buf][ldsoff]);
    }
  };
  auto compute = [&](int buf){
#pragma unroll
    for (int ks = 0; ks < 2; ++ks){
      bf16x8 a[4], b[4];
#pragma unroll
      for (int m = 0; m < 4; ++m){
        int row = wr * 64 + m * 16 + r15;
        int idx = (row * 64 + ks * 32 + kg) ^ ((row & 7) << 3);
        a[m] = *reinterpret_cast<const bf16x8*>(&sA[buf][idx]);
      }
#pragma unroll
      for (int n = 0; n < 4; ++n){
        int row = wc * 64 + n * 16 + r15;
        int idx = (row * 64 + ks * 32 + kg) ^ ((row & 7) << 3);
        b[n] = *reinterpret_cast<const bf16x8*>(&sB[buf][idx]);
      }
#pragma unroll
      for (int m = 0; m < 4; ++m)
#pragma unroll
        for (int n = 0; n < 4; ++n)
          acc[m][n] = __builtin_amdgcn_mfma_f32_16x16x32_bf16(a[m], b[n], acc[m][n], 0, 0, 0);
    }
  };

  constexpr int NK = K / 64;
  stage(0, 0);
  int cur = 0;
#pragma unroll
  for (int t = 0; t < NK; ++t){
    __syncthreads();
    if (t + 1 < NK) stage(cur ^ 1, (t + 1) * 64);
    compute(cur);
    cur ^= 1;
  }

#pragma unroll
  for (int m = 0; m < 4; ++m){
#pragma unroll
    for (int n = 0; n < 4; ++n){
      int c = col0 + n * 16 + r15;
      float bsv = bias ? bias[c] : 0.f;
      int cs = PERM ? pi(c) : c;
#pragma unroll
      for (int q = 0; q < 4; ++q){
        int r = row0 + m * 16 + (lane >> 4) * 4 + q;
        if (r < M){
          float v = acc[m][n][q] + bsv;
          if (act) v = (v > 0.f) ? v : expm1f(v);
          C[(size_t)r * Ncols + cs] = f2b(v);
        }
      }
    }
  }
  if (a_s){
    __syncthreads();
    float* sred = reinterpret_cast<float*>(&sA[0][0]);   // [2][128]
    float* dred = sred + 256;
    const int head = blockIdx.y;
    const int cin = wc * 64;
    float asv[4], adv[4];
#pragma unroll
    for (int n = 0; n < 4; ++n){
      int c = head * EMB + cin + n * 16 + r15;
      asv[n] = a_s[c]; adv[n] = a_d[c];
    }
#pragma unroll
    for (int m = 0; m < 4; ++m){
#pragma unroll
      for (int q = 0; q < 4; ++q){
        float ps = acc[m][0][q] * asv[0] + acc[m][1][q] * asv[1]
                 + acc[m][2][q] * asv[2] + acc[m][3][q] * asv[3];
        float pd = acc[m][0][q] * adv[0] + acc[m][1][q] * adv[1]
                 + acc[m][2][q] * adv[2] + acc[m][3][q] * adv[3];
#pragma unroll
        for (int off = 1; off < 16; off <<= 1){
          ps += __shfl_xor(ps, off);
          pd += __shfl_xor(pd, off);
        }
        if (r15 == 0){
          int rowl = wr * 64 + m * 16 + (lane >> 4) * 4 + q;
          sred[wc * 128 + rowl] = ps;
          dred[wc * 128 + rowl] = pd;
        }
      }
    }
    __syncthreads();
    if (threadIdx.x < 128){
      int rowl = threadIdx.x;
      int r = brow + rowl;
      if (r < M){
        als[(size_t)r * 3 + head] = sred[rowl] + sred[128 + rowl];
        ald[(size_t)r * 3 + head] = dred[rowl] + dred[128 + rowl];
      }
    }
  }
}

// ---------------- fused dependent GEMM ----------------
// T = A@B1^T + bias1 (K=384, LDS dbuf) kept in LDS; then per 128-col chunk
// C_chunk = T@B2_chunk^T (+bias2)(+elu). NCH==3: pi store + als/ald epilogue.
// FINAL: no C store; per-chunk dot with w2 accumulated in LDS -> sigmoid out.
// B2 chunk-0's first half (rows 0-63 -> sB[0]) staged during stage-1's final
// K-step (sB[0] dead there: last read was t=NK-2's compute, fenced by barrier).
template<int NCH, bool FINAL>
__global__ __launch_bounds__(256, 2) void k_fused(const unsigned short* __restrict__ A,
                                                  const unsigned short* __restrict__ B1,
                                                  const float* __restrict__ bias1,
                                                  const unsigned short* __restrict__ B2,
                                                  const float* __restrict__ bias2,
                                                  unsigned short* __restrict__ C,
                                                  const float* __restrict__ a_s,
                                                  const float* __restrict__ a_d,
                                                  float* __restrict__ als, float* __restrict__ ald,
                                                  const float* __restrict__ w2,
                                                  const float* __restrict__ b2s,
                                                  float* __restrict__ outp,
                                                  int M, int act2){
  __shared__ unsigned short sA[2][8192];   // stage-1 A dbuf; then T[128][128] swizzled
  __shared__ unsigned short sB[2][8192];   // stage-1 B dbuf; then B2 chunk (32KB)
  __shared__ float sred[2][128];
  __shared__ float dred[2][128];
  __shared__ float zsum[2][128];
  const int lane = threadIdx.x & 63;
  const int wave = threadIdx.x >> 6;
  const int brow = blockIdx.x * 128;
  const int wr = wave >> 1, wc = wave & 1;
  const int r15 = lane & 15;
  const int kg = (lane >> 4) * 8;
  const int qrow = (lane >> 4) * 4;
  f32x4 acc[4][4] = {};
  const int cbase = wave * 64 + lane;
  unsigned short* Bs = &sB[0][0];

  if (FINAL && threadIdx.x < 128){ zsum[0][threadIdx.x] = 0.f; zsum[1][threadIdx.x] = 0.f; }

  auto stageB2 = [&](int cc, int jlo, int jhi){
    for (int j = jlo; j < jhi; ++j){
      int c = cbase + j * 256;     // 128 rows x 16 chunks (CPR=16)
      int r = c >> 4;
      int cr = c & 15;
      int k0 = ((cr & 8) | ((cr ^ r) & 7)) * 8;
      int ldsoff = (wave * 64 + j * 256) * 8;
      gload16(&B2[(size_t)(cc * 128 + r) * 128 + k0], &Bs[ldsoff]);
    }
  };

  // ---- stage 1: T = A(pi)@B1^T, K=384, BK=64 double-buffered ----
  auto stage1 = [&](int buf, int kt){
#pragma unroll
    for (int j = 0; j < 4; ++j){
      int c = cbase + j * 256;
      int r = c >> 3;
      int k0 = ((c ^ r) & 7) * 8;
      int ldsoff = (wave * 64 + j * 256) * 8;
      int ra = brow + r; if (ra >= M) ra = M - 1;
      gload16(&A[(size_t)ra * HE + kt + k0], &sA[buf][ldsoff]);
      gload16(&B1[(size_t)r * HE + kt + k0], &sB[buf][ldsoff]);
    }
  };
  stage1(0, 0);
  int cur = 0;
#pragma unroll
  for (int t = 0; t < 6; ++t){
    __syncthreads();
    if (t + 1 < 6) stage1(cur ^ 1, (t + 1) * 64);
    else stageB2(0, 0, 4);   // rows 0-63 of chunk0 -> sB[0] (dead this step)
#pragma unroll
    for (int ks = 0; ks < 2; ++ks){
      bf16x8 a[4], b[4];
#pragma unroll
      for (int m = 0; m < 4; ++m){
        int row = wr * 64 + m * 16 + r15;
        int idx = (row * 64 + ks * 32 + kg) ^ ((row & 7) << 3);
        a[m] = *reinterpret_cast<const bf16x8*>(&sA[cur][idx]);
      }
#pragma unroll
      for (int n = 0; n < 4; ++n){
        int row = wc * 64 + n * 16 + r15;
        int idx = (row * 64 + ks * 32 + kg) ^ ((row & 7) << 3);
        b[n] = *reinterpret_cast<const bf16x8*>(&sB[cur][idx]);
      }
#pragma unroll
      for (int m = 0; m < 4; ++m)
#pragma unroll
        for (int n = 0; n < 4; ++n)
          acc[m][n] = __builtin_amdgcn_mfma_f32_16x16x32_bf16(a[m], b[n], acc[m][n], 0, 0, 0);
    }
    cur ^= 1;
  }
  __syncthreads();   // all stage-1 LDS reads done (+ chunk0 first-half landed)
  unsigned short* T = &sA[0][0];
#pragma unroll
  for (int m = 0; m < 4; ++m){
#pragma unroll
    for (int n = 0; n < 4; ++n){
      int col = wc * 64 + n * 16 + r15;
      float bv = bias1[col];
#pragma unroll
      for (int q = 0; q < 4; ++q){
        int row = wr * 64 + m * 16 + qrow + q;
        T[(row * 128 + col) ^ ((row & 7) << 3)] = f2b(acc[m][n][q] + bv);
      }
    }
  }

  // ---- stage 2: per 128-col chunk ----
#pragma unroll
  for (int cc = 0; cc < NCH; ++cc){
    if (cc == 0){
      __syncthreads();           // T visible; stage-1 sB[1] reads done
      stageB2(0, 4, 8);          // rows 64-127 of chunk0 -> sB[1]
    } else {
      __syncthreads();           // prev chunk's Bs reads done
      stageB2(cc, 0, 8);
    }
    __syncthreads();             // staged chunk visible
#pragma unroll
    for (int m = 0; m < 4; ++m)
#pragma unroll
      for (int n = 0; n < 4; ++n)
        acc[m][n] = (f32x4){0.f, 0.f, 0.f, 0.f};
#pragma unroll
    for (int ks = 0; ks < 4; ++ks){
      bf16x8 a[4], b[4];
#pragma unroll
      for (int m = 0; m < 4; ++m){
        int row = wr * 64 + m * 16 + r15;
        int idx = (row * 128 + ks * 32 + kg) ^ ((row & 7) << 3);
        a[m] = *reinterpret_cast<const bf16x8*>(&T[idx]);
      }
#pragma unroll
      for (int n = 0; n < 4; ++n){
        int row = wc * 64 + n * 16 + r15;
        int idx = (row * 128 + ks * 32 + kg) ^ ((row & 7) << 3);
        b[n] = *reinterpret_cast<const bf16x8*>(&Bs[idx]);
      }
#pragma unroll
      for (int m = 0; m < 4; ++m)
#pragma unroll
        for (int n = 0; n < 4; ++n)
          acc[m][n] = __builtin_amdgcn_mfma_f32_16x16x32_bf16(a[m], b[n], acc[m][n], 0, 0, 0);
    }
    if (FINAL){
      float w2v[4];
#pragma unroll
      for (int n = 0; n < 4; ++n)
        w2v[n] = w2[cc * 128 + wc * 64 + n * 16 + r15];
#pragma unroll
      for (int m = 0; m < 4; ++m){
#pragma unroll
        for (int q = 0; q < 4; ++q){
          float p = 0.f;
#pragma unroll
          for (int n = 0; n < 4; ++n){
            float v = acc[m][n][q] + bias2[cc * 128 + wc * 64 + n * 16 + r15];
            v = (v > 0.f) ? v : expm1f(v);
            p += v * w2v[n];
          }
#pragma unroll
          for (int off = 1; off < 16; off <<= 1) p += __shfl_xor(p, off);
          if (r15 == 0) zsum[wc][wr * 64 + m * 16 + qrow + q] += p;
        }
      }
    } else {
#pragma unroll
      for (int m = 0; m < 4; ++m){
#pragma unroll
        for (int n = 0; n < 4; ++n){
          int cglob = cc * 128 + wc * 64 + n * 16 + r15;
          float bv = bias2 ? bias2[cglob] : 0.f;
          int cs = (NCH == 3) ? pi(cglob) : cglob;
          const int ncols = (NCH == 3) ? HE : 512;
#pragma unroll
          for (int q = 0; q < 4; ++q){
            int rg = brow + wr * 64 + m * 16 + qrow + q;
            if (rg < M){
              float v = acc[m][n][q] + bv;
              if (act2) v = (v > 0.f) ? v : expm1f(v);
              C[(size_t)rg * ncols + cs] = f2b(v);
            }
          }
        }
      }
    }
    if (a_s){
      const int cin = wc * 64;
      float asv[4], adv[4];
#pragma unroll
      for (int n = 0; n < 4; ++n){
        int cglob = cc * 128 + cin + n * 16 + r15;
        asv[n] = a_s[cglob]; adv[n] = a_d[cglob];
      }
#pragma unroll
      for (int m = 0; m < 4; ++m){
#pragma unroll
        for (int q = 0; q < 4; ++q){
          float ps = acc[m][0][q] * asv[0] + acc[m][1][q] * asv[1]
                   + acc[m][2][q] * asv[2] + acc[m][3][q] * asv[3];
          float pd = acc[m][0][q] * adv[0] + acc[m][1][q] * adv[1]
                   + acc[m][2][q] * adv[2] + acc[m][3][q] * adv[3];
#pragma unroll
          for (int off = 1; off < 16; off <<= 1){
            ps += __shfl_xor(ps, off);
            pd += __shfl_xor(pd, off);
          }
          if (r15 == 0){
            int rowl = wr * 64 + m * 16 + qrow + q;
            sred[wc][rowl] = ps;
            dred[wc][rowl] = pd;
          }
        }
      }
      __syncthreads();
      if (threadIdx.x < 128){
        int rowl = threadIdx.x;
        int rg = brow + rowl;
        if (rg < M){
          als[(size_t)rg * 3 + cc] = sred[0][rowl] + sred[1][rowl];
          ald[(size_t)rg * 3 + cc] = dred[0][rowl] + dred[1][rowl];
        }
      }
    }
  }
  if (FINAL){
    __syncthreads();
    if (threadIdx.x < 128){
      int rg = brow + threadIdx.x;
      if (rg < M){
        float z = zsum[0][threadIdx.x] + zsum[1][threadIdx.x] + b2s[0];
        outp[rg] = 1.f / (1.f + __expf(-z));
      }
    }
  }
}

// ---------------- GAT aggregation (1 wave/node, barrier-free) + inline self-loop ----
__global__ __launch_bounds__(256) void k_agg(const unsigned short* __restrict__ h,
                                             const float* __restrict__ als,
                                             const float* __restrict__ ald,
                                             const int* __restrict__ rs, const int* __restrict__ cntp,
                                             const int* __restrict__ esrc,
                                             const float* __restrict__ bias,
                                             unsigned short* __restrict__ out, int Nn){
  __shared__ float exs[4][EXCAP * 3];      // 12 KB: per-wave ex cache
  int wave = threadIdx.x >> 6;
  int n = blockIdx.x * 4 + wave;
  int lane = threadIdx.x & 63;
  if (n >= Nn) return;
  int start = rs[n];
  int end = start + cntp[n];
  f32x3 adn = *reinterpret_cast<const f32x3*>(&ald[(size_t)n * 3]);
  f32x3 asn = *reinterpret_cast<const f32x3*>(&als[(size_t)n * 3]);
  float es0 = __expf(lrelu(asn.x + adn.x));   // self-loop term (wave-uniform)
  float es1 = __expf(lrelu(asn.y + adn.y));
  float es2 = __expf(lrelu(asn.z + adn.z));
  float d0 = 0.f, d1 = 0.f, d2 = 0.f;
  for (int i = start + lane; i < end; i += 64){
    int s = esrc[i];
    f32x3 as = *reinterpret_cast<const f32x3*>(&als[(size_t)s * 3]);
    float e0 = __expf(lrelu(as.x + adn.x));
    float e1 = __expf(lrelu(as.y + adn.y));
    float e2 = __expf(lrelu(as.z + adn.z));
    d0 += e0; d1 += e1; d2 += e2;
    int j = i - start;
    if (j < EXCAP){
      exs[wave][j * 3 + 0] = e0;
      exs[wave][j * 3 + 1] = e1;
      exs[wave][j * 3 + 2] = e2;
    }
  }
  for (int off = 32; off; off >>= 1){
    d0 += __shfl_xor(d0, off);
    d1 += __shfl_xor(d1, off);
    d2 += __shfl_xor(d2, off);
  }
  d0 += es0; d1 += es1; d2 += es2;
  float iv[3] = {1.f / (d0 + 1e-16f), 1.f / (d1 + 1e-16f), 1.f / (d2 + 1e-16f)};
  const int l3 = lane * 3;
  float acc[6];
  {
    u32x3 v = *reinterpret_cast<const u32x3*>(reinterpret_cast<const unsigned*>(h + (size_t)n * HE) + l3);
    acc[0] = es0 * b2f((unsigned short)v.x);
    acc[1] = es0 * b2f((unsigned short)(v.x >> 16));
    acc[2] = es1 * b2f((unsigned short)v.y);
    acc[3] = es1 * b2f((unsigned short)(v.y >> 16));
    acc[4] = es2 * b2f((unsigned short)v.z);
    acc[5] = es2 * b2f((unsigned short)(v.z >> 16));
  }
  const float* exw = exs[wave];
  int i = start;
  int nfast = end;
  if (end - start > EXCAP) nfast = start + EXCAP;
  for (; i + 3 < nfast; i += 4){
    u32x3 hv[4]; f32x3 ev[4];
#pragma unroll
    for (int u = 0; u < 4; ++u){
      int s = esrc[i + u];
      hv[u] = *reinterpret_cast<const u32x3*>(reinterpret_cast<const unsigned*>(h + (size_t)s * HE) + l3);
      int j = (i + u - start) * 3;
      ev[u].x = exw[j]; ev[u].y = exw[j + 1]; ev[u].z = exw[j + 2];
    }
#pragma unroll
    for (int u = 0; u < 4; ++u){
      acc[0] += ev[u].x * b2f((unsigned short)hv[u].x);
      acc[1] += ev[u].x * b2f((unsigned short)(hv[u].x >> 16));
      acc[2] += ev[u].y * b2f((unsigned short)hv[u].y);
      acc[3] += ev[u].y * b2f((unsigned short)(hv[u].y >> 16));
      acc[4] += ev[u].z * b2f((unsigned short)hv[u].z);
      acc[5] += ev[u].z * b2f((unsigned short)(hv[u].z >> 16));
    }
  }
  for (; i < end; ++i){
    int j = i - start;
    int s = esrc[i];
    float e0, e1, e2;
    if (j < EXCAP){
      e0 = exw[j * 3]; e1 = exw[j * 3 + 1]; e2 = exw[j * 3 + 2];
    } else {
      f32x3 as = *reinterpret_cast<const f32x3*>(&als[(size_t)s * 3]);
      e0 = __expf(lrelu(as.x + adn.x));
      e1 = __expf(lrelu(as.y + adn.y));
      e2 = __expf(lrelu(as.z + adn.z));
    }
    u32x3 v = *reinterpret_cast<const u32x3*>(reinterpret_cast<const unsigned*>(h + (size_t)s * HE) + l3);
    acc[0] += e0 * b2f((unsigned short)v.x);
    acc[1] += e0 * b2f((unsigned short)(v.x >> 16));
    acc[2] += e1 * b2f((unsigned short)v.y);
    acc[3] += e1 * b2f((unsigned short)(v.y >> 16));
    acc[4] += e2 * b2f((unsigned short)v.z);
    acc[5] += e2 * b2f((unsigned short)(v.z >> 16));
  }
  unsigned ov[3];
#pragma unroll
  for (int hh = 0; hh < 3; ++hh){
    int ch = 128 * hh + 2 * lane;
    float v0 = acc[2 * hh] * iv[hh] + bias[ch];
    float v1 = acc[2 * hh + 1] * iv[hh] + bias[ch + 1];
    v0 = (v0 > 0.f) ? v0 : expm1f(v0);
    v1 = (v1 > 0.f) ? v1 : expm1f(v1);
    ov[hh] = (unsigned)f2b(v0) | ((unsigned)f2b(v1) << 16);
  }
  unsigned* orow = reinterpret_cast<unsigned*>(out + (size_t)n * HE) + l3;
  *reinterpret_cast<u32x3*>(orow) = *reinterpret_cast<u32x3*>(ov);
}

extern "C" void kernel_launch(void* const* d_in, const int* in_sizes, int n_in,
                              void* d_out, int out_size, void* d_ws, size_t ws_size,
                              hipStream_t stream){
  const float* x   = (const float*)d_in[0];
  const int*   ei  = (const int*)d_in[1];
  const int N = in_sizes[0] / F_IN;
  const int E = in_sizes[1] / 2;
  const float* W[3]  = {(const float*)d_in[2], (const float*)d_in[6], (const float*)d_in[10]};
  const float* AS[3] = {(const float*)d_in[3], (const float*)d_in[7], (const float*)d_in[11]};
  const float* AD[3] = {(const float*)d_in[4], (const float*)d_in[8], (const float*)d_in[12]};
  const float* BB[3] = {(const float*)d_in[5], (const float*)d_in[9], (const float*)d_in[13]};
  const float* WH[3] = {(const float*)d_in[14], (const float*)d_in[16], (const float*)d_in[18]};
  const float* BH[3] = {(const float*)d_in[15], (const float*)d_in[17], (const float*)d_in[19]};
  const float* Wl1 = (const float*)d_in[20];
  const float* bl1 = (const float*)d_in[21];
  const float* Wl2 = (const float*)d_in[22];
  const float* bl2 = (const float*)d_in[23];
  float* out = (float*)d_out;

  // ---- workspace layout ----
  char* ws = (char*)d_ws;
  size_t off = 0;
  auto alloc = [&](size_t bytes) -> char* {
    char* p = ws + off;
    off = (off + bytes + 255) & ~(size_t)255;
    return p;
  };
  int*   row_start = (int*)alloc((size_t)N * 4);
  int*   cnt       = (int*)alloc((size_t)N * 4);
  int*   esrc      = (int*)alloc((size_t)E * 4);
  int*   rank      = (int*)alloc((size_t)E * 4);
  int*   cursor    = (int*)alloc(256);
  float* als       = (float*)alloc((size_t)N * 3 * 4);
  float* ald       = (float*)alloc((size_t)N * 3 * 4);
  unsigned short* xb = (unsigned short*)alloc((size_t)N * F_IN * 2);   // x bf16
  unsigned short* P  = (unsigned short*)alloc((size_t)N * HE * 2);     // h (pi layout)
  unsigned short* Q  = (unsigned short*)alloc((size_t)N * HE * 2);     // agg out (pi layout)
  // weight slabs
  unsigned short* W1T  = (unsigned short*)alloc((size_t)F_IN * HE * 2);  // [384,128]
  unsigned short* W2T  = (unsigned short*)alloc((size_t)F_IN * HE * 2);
  unsigned short* W3T  = (unsigned short*)alloc((size_t)F_IN * HE * 2);
  unsigned short* WhPT[3];
  for (int l = 0; l < 3; ++l)
    WhPT[l] = (unsigned short*)alloc((size_t)HE * F_IN * 2);            // [128,384] K pi-permuted
  unsigned short* Wl1T = (unsigned short*)alloc((size_t)F_IN * 512 * 2); // [512,128]

  // ---- single prep dispatch: x->bf16, all weight transposes, cnt+cursor zero ----
  const int n4 = N * F_IN / 4;
  const int prep_total = n4 + 6 * S1 + S3 + N + 1;
  k_prep<<<(prep_total + 255) / 256, 256, 0, stream>>>(
      x, xb, n4, W[0], W[1], W[2], W1T, W2T, W3T,
      WH[0], WH[1], WH[2], WhPT[0], WhPT[1], WhPT[2], Wl1, Wl1T, cnt, cursor, N);

  // ---- CSR by dst (real edges; single atomic hist + wave-scan offsets) ----
  k_hist<<<2048, 256, 0, stream>>>(ei, E, cnt, rank);
  k_offsets<<<(N + 255) / 256, 256, 0, stream>>>(cnt, row_start, cursor, N);
  k_scatter<<<2048, 256, 0, stream>>>(ei, E, row_start, rank, esrc);

  const int mb = (N + 127) / 128;
  const int nwave = (N + 3) / 4;

  // ---- layer 1: P = x@W1 (pi store) + als/ald; agg ----
  k_mgemm<128, true><<<dim3(mb, 3), 256, 0, stream>>>(xb, W1T, nullptr, P,
      AS[0], AD[0], als, ald, N, HE, 0);
  k_agg<<<nwave, 256, 0, stream>>>(P, als, ald, row_start, cnt, esrc, BB[0], Q, N);
  // ---- layer 2: fused (R1 = Q@Wh1+bh1) -> P = R1@W2 (pi) + als/ald; agg ----
  k_fused<3, false><<<mb, 256, 0, stream>>>(Q, WhPT[0], BH[0], W2T, nullptr, P,
      AS[1], AD[1], als, ald, nullptr, nullptr, nullptr, N, 0);
  k_agg<<<nwave, 256, 0, stream>>>(P, als, ald, row_start, cnt, esrc, BB[1], Q, N);
  // ---- layer 3 ----
  k_fused<3, false><<<mb, 256, 0, stream>>>(Q, WhPT[1], BH[1], W3T, nullptr, P,
      AS[2], AD[2], als, ald, nullptr, nullptr, nullptr, N, 0);
  k_agg<<<nwave, 256, 0, stream>>>(P, als, ald, row_start, cnt, esrc, BB[2], Q, N);
  // ---- MLP + head fused ----
  k_fused<4, true><<<mb, 256, 0, stream>>>(Q, WhPT[2], BH[2], Wl1T, bl1, nullptr,
      nullptr, nullptr, nullptr, nullptr, Wl2, bl2, out, N, 1);
}

// Round 15
// 525.404 us; speedup vs baseline: 1.1211x; 1.1211x over previous
//
#include <hip/hip_runtime.h>
#include <hip/hip_bf16.h>
#include <cstdint>
#include <cstddef>

// GuidedGNN: 3x GATConv(H=3, EMB=128, concat) + head transforms + MLP head.
// R12 fix: __builtin_amdgcn_cvt_f32_fp8 requires constant sel -> template<SEL>.
// P (gather operand, consumed ONLY by k_agg) stored as fp8 e4m3 -> gather
// bytes halve AND working set (19.2 MB) nearly L2-fits. Q/weights stay bf16.

#define F_IN 128
#define EMB  128
#define NH   3
#define HE   (NH*EMB)   // 384
#define EXCAP 256       // per-wave LDS ex-cache entries (max real deg ~45)

typedef __attribute__((ext_vector_type(8))) short bf16x8;
typedef __attribute__((ext_vector_type(4))) float f32x4;

__device__ __forceinline__ float lrelu(float x){ return x > 0.f ? x : 0.2f * x; }
__device__ __forceinline__ float b2f(unsigned short u){ return __uint_as_float((unsigned)u << 16); }
__device__ __forceinline__ unsigned short f2b(float f){
  __hip_bfloat16 h = __float2bfloat16(f);
  return *reinterpret_cast<unsigned short*>(&h);
}
// channel permutation: orig c in [0,384) -> (c%128/2)*6 + head*2 + (c&1)
__device__ __forceinline__ int pi(int c){
  int hh = c >> 7, w = c & 127;
  return (w >> 1) * 6 + hh * 2 + (w & 1);
}
__device__ __forceinline__ void gload16(const unsigned short* g, unsigned short* l){
  __builtin_amdgcn_global_load_lds((const __attribute__((address_space(1))) unsigned int*)g,
                                   (__attribute__((address_space(3))) unsigned int*)l, 16, 0, 0);
}

// ---- fp8 e4m3 (OCP on gfx950) helpers; sel must be a compile-time constant ----
#if __has_builtin(__builtin_amdgcn_cvt_pk_fp8_f32)
__device__ __forceinline__ unsigned char f2fp8(float f){
  int r = __builtin_amdgcn_cvt_pk_fp8_f32(f, f, 0, false);
  return (unsigned char)(r & 0xff);
}
#else
__device__ __forceinline__ unsigned char f2fp8(float f){
  float a = fabsf(f);
  unsigned s = (__float_as_uint(f) >> 31) << 7;
  if (a < 7.8125e-3f) return (unsigned char)s;
  a = fminf(a, 448.f);
  unsigned u = __float_as_uint(a);
  int e = (int)(u >> 23) - 127;
  unsigned m = (u >> 20) & 7;
  unsigned rest = u & 0xFFFFF;
  if (rest > 0x80000 || (rest == 0x80000 && (m & 1))){ m++; if (m == 8){ m = 0; e++; } }
  if (e > 8){ e = 8; m = 7; }
  if (e < -6){ e = -6; }   // imperfect near-subnormal; fallback only
  return (unsigned char)(s | ((unsigned)(e + 7) << 3) | m);
}
#endif
#if __has_builtin(__builtin_amdgcn_cvt_f32_fp8)
template<int SEL>
__device__ __forceinline__ float fp8f(unsigned int u){
  return __builtin_amdgcn_cvt_f32_fp8(u, SEL);
}
#else
template<int SEL>
__device__ __forceinline__ float fp8f(unsigned int u){
  unsigned char b = (u >> (8 * SEL)) & 0xff;
  int e = (b >> 3) & 15, m = b & 7;
  float v = (e == 0) ? (float)m * 0.001953125f
                     : (float)(8 + m) * exp2f((float)(e - 10));
  return (b & 0x80) ? -v : v;
}
#endif

struct f32x3 { float x, y, z; };

// ---------------- combined prep: x->bf16, weight transposes, cnt/cursor zero ----------------
#define S1 49152   // 128*384
#define S3 65536   // 128*512
__global__ void k_prep(const float* __restrict__ x, unsigned short* __restrict__ xb, int n4,
                       const float* __restrict__ W1, const float* __restrict__ W2,
                       const float* __restrict__ W3,
                       unsigned short* __restrict__ W1T, unsigned short* __restrict__ W2T,
                       unsigned short* __restrict__ W3T,
                       const float* __restrict__ Wh1, const float* __restrict__ Wh2,
                       const float* __restrict__ Wh3,
                       unsigned short* __restrict__ Wh1T, unsigned short* __restrict__ Wh2T,
                       unsigned short* __restrict__ Wh3T,
                       const float* __restrict__ Wl1, unsigned short* __restrict__ Wl1T,
                       int* __restrict__ cnt, int* __restrict__ cursor, int Nn){
  int i = blockIdx.x * 256 + threadIdx.x;
  if (i < n4){
    float4 v = reinterpret_cast<const float4*>(x)[i];
    unsigned short o[4] = {f2b(v.x), f2b(v.y), f2b(v.z), f2b(v.w)};
    *reinterpret_cast<uint2*>(&xb[i * 4]) = *reinterpret_cast<uint2*>(o);
    return;
  }
  i -= n4;
  if (i < 3 * S1){  // W1/W2/W3 [128,384] -> [384,128]
    const float* Wsrc = (i < S1) ? W1 : (i < 2 * S1) ? W2 : W3;
    unsigned short* Wdst = (i < S1) ? W1T : (i < 2 * S1) ? W2T : W3T;
    int j = i % S1;
    int r = j / HE, c = j % HE;
    Wdst[(size_t)c * F_IN + r] = f2b(Wsrc[j]);
    return;
  }
  i -= 3 * S1;
  if (i < 3 * S1){  // Wh1/2/3 [384,128] -> [128 cols][384] K pi-permuted
    const float* Wsrc = (i < S1) ? Wh1 : (i < 2 * S1) ? Wh2 : Wh3;
    unsigned short* Wdst = (i < S1) ? Wh1T : (i < 2 * S1) ? Wh2T : Wh3T;
    int j = i % S1;
    int r = j / F_IN, c = j % F_IN;
    Wdst[(size_t)c * HE + pi(r)] = f2b(Wsrc[j]);
    return;
  }
  i -= 3 * S1;
  if (i < S3){      // Wl1 [128,512] -> [512,128]
    int r = i / 512, c = i % 512;
    Wl1T[(size_t)c * F_IN + r] = f2b(Wl1[i]);
    return;
  }
  i -= S3;
  if (i < Nn){ cnt[i] = 0; return; }
  i -= Nn;
  if (i == 0) cursor[0] = 0;
}

// ---------------- CSR build (real edges only; self-loops handled in k_agg) ----------------
__global__ void k_hist(const int* __restrict__ ei, int E, int* __restrict__ cnt,
                       int* __restrict__ rank){
  for (int i = blockIdx.x * blockDim.x + threadIdx.x; i < E; i += gridDim.x * blockDim.x){
    int d = ei[E + i];
    rank[i] = atomicAdd(&cnt[d], 1);
  }
}

// one-dispatch offsets: wave shfl-scan + global cursor.
__global__ void k_offsets(const int* __restrict__ cnt, int* __restrict__ rs,
                          int* __restrict__ cursor, int Nn){
  int n = blockIdx.x * 256 + threadIdx.x;
  int lane = threadIdx.x & 63;
  int v = (n < Nn) ? cnt[n] : 0;
  int inc = v;
#pragma unroll
  for (int off = 1; off < 64; off <<= 1){
    int t = __shfl_up(inc, off);
    if (lane >= off) inc += t;
  }
  int total = __shfl(inc, 63);
  int base = 0;
  if (lane == 0) base = atomicAdd(cursor, total);
  base = __shfl(base, 0);
  if (n < Nn) rs[n] = base + inc - v;
}

__global__ void k_scatter(const int* __restrict__ ei, int E, const int* __restrict__ rs,
                          const int* __restrict__ rank, int* __restrict__ esrc){
  for (int i = blockIdx.x * blockDim.x + threadIdx.x; i < E; i += gridDim.x * blockDim.x){
    esrc[rs[ei[E + i]] + rank[i]] = ei[i];
  }
}

// ---------------- LDS-pipelined MFMA GEMM (layer-1) ----------------
// PERM: store fp8-e4m3 into pi-permuted byte layout (C reinterpreted as bytes).
template<int K, bool PERM>
__global__ __launch_bounds__(256, 2) void k_mgemm(const unsigned short* __restrict__ A,
                                                  const unsigned short* __restrict__ BT,
                                                  const float* __restrict__ bias,
                                                  unsigned short* __restrict__ C,
                                                  const float* __restrict__ a_s,
                                                  const float* __restrict__ a_d,
                                                  float* __restrict__ als, float* __restrict__ ald,
                                                  int M, int Ncols, int act){
  __shared__ unsigned short sA[2][8192];   // [buf][128 rows x 64 k] swizzled
  __shared__ unsigned short sB[2][8192];
  const int lane = threadIdx.x & 63;
  const int wave = threadIdx.x >> 6;
  const int brow = blockIdx.x * 128;
  const int bcol = blockIdx.y * 128;
  const int wr = wave >> 1, wc = wave & 1;
  const int r15 = lane & 15;
  const int kg = (lane >> 4) * 8;
  const int row0 = brow + wr * 64;
  const int col0 = bcol + wc * 64;
  f32x4 acc[4][4] = {};

  const int cbase = wave * 64 + lane;
  auto stage = [&](int buf, int kt){
#pragma unroll
    for (int j = 0; j < 4; ++j){
      int c = cbase + j * 256;
      int r = c >> 3;
      int k0 = ((c ^ r) & 7) * 8;
      int ldsoff = (wave * 64 + j * 256) * 8;   // wave-uniform; HW adds lane*16B
      int ra = brow + r; if (ra >= M) ra = M - 1;
      gload16(&A[(size_t)ra * K + kt + k0], &sA[buf][ldsoff]);
      gload16(&BT[(size_t)(bcol + r) * K + kt + k0], &sB[buf][ldsoff]);
    }
  };
  auto compute = [&](int buf){
#pragma unroll
    for (int ks = 0; ks < 2; ++ks){
      bf16x8 a[4], b[4];
#pragma unroll
      for (int m = 0; m < 4; ++m){
        int row = wr * 64 + m * 16 + r15;
        int idx = (row * 64 + ks * 32 + kg) ^ ((row & 7) << 3);
        a[m] = *reinterpret_cast<const bf16x8*>(&sA[buf][idx]);
      }
#pragma unroll
      for (int n = 0; n < 4; ++n){
        int row = wc * 64 + n * 16 + r15;
        int idx = (row * 64 + ks * 32 + kg) ^ ((row & 7) << 3);
        b[n] = *reinterpret_cast<const bf16x8*>(&sB[buf][idx]);
      }
#pragma unroll
      for (int m = 0; m < 4; ++m)
#pragma unroll
        for (int n = 0; n < 4; ++n)
          acc[m][n] = __builtin_amdgcn_mfma_f32_16x16x32_bf16(a[m], b[n], acc[m][n], 0, 0, 0);
    }
  };

  constexpr int NK = K / 64;
  stage(0, 0);
  int cur = 0;
#pragma unroll
  for (int t = 0; t < NK; ++t){
    __syncthreads();
    if (t + 1 < NK) stage(cur ^ 1, (t + 1) * 64);
    compute(cur);
    cur ^= 1;
  }

#pragma unroll
  for (int m = 0; m < 4; ++m){
#pragma unroll
    for (int n = 0; n < 4; ++n){
      int c = col0 + n * 16 + r15;
      float bsv = bias ? bias[c] : 0.f;
#pragma unroll
      for (int q = 0; q < 4; ++q){
        int r = row0 + m * 16 + (lane >> 4) * 4 + q;
        if (r < M){
          float v = acc[m][n][q] + bsv;
          if (act) v = (v > 0.f) ? v : expm1f(v);
          if (PERM) reinterpret_cast<unsigned char*>(C)[(size_t)r * Ncols + pi(c)] = f2fp8(v);
          else C[(size_t)r * Ncols + c] = f2b(v);
        }
      }
    }
  }
  if (a_s){
    __syncthreads();
    float* sred = reinterpret_cast<float*>(&sA[0][0]);   // [2][128]
    float* dred = sred + 256;
    const int head = blockIdx.y;
    const int cin = wc * 64;
    float asv[4], adv[4];
#pragma unroll
    for (int n = 0; n < 4; ++n){
      int c = head * EMB + cin + n * 16 + r15;
      asv[n] = a_s[c]; adv[n] = a_d[c];
    }
#pragma unroll
    for (int m = 0; m < 4; ++m){
#pragma unroll
      for (int q = 0; q < 4; ++q){
        float ps = acc[m][0][q] * asv[0] + acc[m][1][q] * asv[1]
                 + acc[m][2][q] * asv[2] + acc[m][3][q] * asv[3];
        float pd = acc[m][0][q] * adv[0] + acc[m][1][q] * adv[1]
                 + acc[m][2][q] * adv[2] + acc[m][3][q] * adv[3];
#pragma unroll
        for (int off = 1; off < 16; off <<= 1){
          ps += __shfl_xor(ps, off);
          pd += __shfl_xor(pd, off);
        }
        if (r15 == 0){
          int rowl = wr * 64 + m * 16 + (lane >> 4) * 4 + q;
          sred[wc * 128 + rowl] = ps;
          dred[wc * 128 + rowl] = pd;
        }
      }
    }
    __syncthreads();
    if (threadIdx.x < 128){
      int rowl = threadIdx.x;
      int r = brow + rowl;
      if (r < M){
        als[(size_t)r * 3 + head] = sred[rowl] + sred[128 + rowl];
        ald[(size_t)r * 3 + head] = dred[rowl] + dred[128 + rowl];
      }
    }
  }
}

// ---------------- fused dependent GEMM ----------------
// T = A@B1^T + bias1 (K=384, LDS dbuf); then per 128-col chunk C = T@B2_chunk^T.
// NCH==3: fp8-pi store + als/ald epilogue. FINAL: dot with w2 -> sigmoid out.
template<int NCH, bool FINAL>
__global__ __launch_bounds__(256, 2) void k_fused(const unsigned short* __restrict__ A,
                                                  const unsigned short* __restrict__ B1,
                                                  const float* __restrict__ bias1,
                                                  const unsigned short* __restrict__ B2,
                                                  const float* __restrict__ bias2,
                                                  unsigned short* __restrict__ C,
                                                  const float* __restrict__ a_s,
                                                  const float* __restrict__ a_d,
                                                  float* __restrict__ als, float* __restrict__ ald,
                                                  const float* __restrict__ w2,
                                                  const float* __restrict__ b2s,
                                                  float* __restrict__ outp,
                                                  int M, int act2){
  __shared__ unsigned short sA[2][8192];   // stage-1 A dbuf; then T[128][128] swizzled
  __shared__ unsigned short sB[2][8192];   // stage-1 B dbuf; then B2 chunk (32KB)
  __shared__ float sred[2][128];
  __shared__ float dred[2][128];
  __shared__ float zsum[2][128];
  const int lane = threadIdx.x & 63;
  const int wave = threadIdx.x >> 6;
  const int brow = blockIdx.x * 128;
  const int wr = wave >> 1, wc = wave & 1;
  const int r15 = lane & 15;
  const int kg = (lane >> 4) * 8;
  const int qrow = (lane >> 4) * 4;
  f32x4 acc[4][4] = {};
  const int cbase = wave * 64 + lane;
  unsigned short* Bs = &sB[0][0];

  if (FINAL && threadIdx.x < 128){ zsum[0][threadIdx.x] = 0.f; zsum[1][threadIdx.x] = 0.f; }

  auto stageB2 = [&](int cc, int jlo, int jhi){
    for (int j = jlo; j < jhi; ++j){
      int c = cbase + j * 256;     // 128 rows x 16 chunks (CPR=16)
      int r = c >> 4;
      int cr = c & 15;
      int k0 = ((cr & 8) | ((cr ^ r) & 7)) * 8;
      int ldsoff = (wave * 64 + j * 256) * 8;
      gload16(&B2[(size_t)(cc * 128 + r) * 128 + k0], &Bs[ldsoff]);
    }
  };

  // ---- stage 1: T = A(pi)@B1^T, K=384, BK=64 double-buffered ----
  auto stage1 = [&](int buf, int kt){
#pragma unroll
    for (int j = 0; j < 4; ++j){
      int c = cbase + j * 256;
      int r = c >> 3;
      int k0 = ((c ^ r) & 7) * 8;
      int ldsoff = (wave * 64 + j * 256) * 8;
      int ra = brow + r; if (ra >= M) ra = M - 1;
      gload16(&A[(size_t)ra * HE + kt + k0], &sA[buf][ldsoff]);
      gload16(&B1[(size_t)r * HE + kt + k0], &sB[buf][ldsoff]);
    }
  };
  stage1(0, 0);
  int cur = 0;
#pragma unroll
  for (int t = 0; t < 6; ++t){
    __syncthreads();
    if (t + 1 < 6) stage1(cur ^ 1, (t + 1) * 64);
    else stageB2(0, 0, 4);   // rows 0-63 of chunk0 -> sB[0] (dead this step)
#pragma unroll
    for (int ks = 0; ks < 2; ++ks){
      bf16x8 a[4], b[4];
#pragma unroll
      for (int m = 0; m < 4; ++m){
        int row = wr * 64 + m * 16 + r15;
        int idx = (row * 64 + ks * 32 + kg) ^ ((row & 7) << 3);
        a[m] = *reinterpret_cast<const bf16x8*>(&sA[cur][idx]);
      }
#pragma unroll
      for (int n = 0; n < 4; ++n){
        int row = wc * 64 + n * 16 + r15;
        int idx = (row * 64 + ks * 32 + kg) ^ ((row & 7) << 3);
        b[n] = *reinterpret_cast<const bf16x8*>(&sB[cur][idx]);
      }
#pragma unroll
      for (int m = 0; m < 4; ++m)
#pragma unroll
        for (int n = 0; n < 4; ++n)
          acc[m][n] = __builtin_amdgcn_mfma_f32_16x16x32_bf16(a[m], b[n], acc[m][n], 0, 0, 0);
    }
    cur ^= 1;
  }
  __syncthreads();   // all stage-1 LDS reads done (+ chunk0 first-half landed)
  unsigned short* T = &sA[0][0];
#pragma unroll
  for (int m = 0; m < 4; ++m){
#pragma unroll
    for (int n = 0; n < 4; ++n){
      int col = wc * 64 + n * 16 + r15;
      float bv = bias1[col];
#pragma unroll
      for (int q = 0; q < 4; ++q){
        int row = wr * 64 + m * 16 + qrow + q;
        T[(row * 128 + col) ^ ((row & 7) << 3)] = f2b(acc[m][n][q] + bv);
      }
    }
  }

  // ---- stage 2: per 128-col chunk ----
#pragma unroll
  for (int cc = 0; cc < NCH; ++cc){
    if (cc == 0){
      __syncthreads();           // T visible; stage-1 sB[1] reads done
      stageB2(0, 4, 8);          // rows 64-127 of chunk0 -> sB[1]
    } else {
      __syncthreads();           // prev chunk's Bs reads done
      stageB2(cc, 0, 8);
    }
    __syncthreads();             // staged chunk visible
#pragma unroll
    for (int m = 0; m < 4; ++m)
#pragma unroll
      for (int n = 0; n < 4; ++n)
        acc[m][n] = (f32x4){0.f, 0.f, 0.f, 0.f};
#pragma unroll
    for (int ks = 0; ks < 4; ++ks){
      bf16x8 a[4], b[4];
#pragma unroll
      for (int m = 0; m < 4; ++m){
        int row = wr * 64 + m * 16 + r15;
        int idx = (row * 128 + ks * 32 + kg) ^ ((row & 7) << 3);
        a[m] = *reinterpret_cast<const bf16x8*>(&T[idx]);
      }
#pragma unroll
      for (int n = 0; n < 4; ++n){
        int row = wc * 64 + n * 16 + r15;
        int idx = (row * 128 + ks * 32 + kg) ^ ((row & 7) << 3);
        b[n] = *reinterpret_cast<const bf16x8*>(&Bs[idx]);
      }
#pragma unroll
      for (int m = 0; m < 4; ++m)
#pragma unroll
        for (int n = 0; n < 4; ++n)
          acc[m][n] = __builtin_amdgcn_mfma_f32_16x16x32_bf16(a[m], b[n], acc[m][n], 0, 0, 0);
    }
    if (FINAL){
      float w2v[4];
#pragma unroll
      for (int n = 0; n < 4; ++n)
        w2v[n] = w2[cc * 128 + wc * 64 + n * 16 + r15];
#pragma unroll
      for (int m = 0; m < 4; ++m){
#pragma unroll
        for (int q = 0; q < 4; ++q){
          float p = 0.f;
#pragma unroll
          for (int n = 0; n < 4; ++n){
            float v = acc[m][n][q] + bias2[cc * 128 + wc * 64 + n * 16 + r15];
            v = (v > 0.f) ? v : expm1f(v);
            p += v * w2v[n];
          }
#pragma unroll
          for (int off = 1; off < 16; off <<= 1) p += __shfl_xor(p, off);
          if (r15 == 0) zsum[wc][wr * 64 + m * 16 + qrow + q] += p;
        }
      }
    } else {
#pragma unroll
      for (int m = 0; m < 4; ++m){
#pragma unroll
        for (int n = 0; n < 4; ++n){
          int cglob = cc * 128 + wc * 64 + n * 16 + r15;
          float bv = bias2 ? bias2[cglob] : 0.f;
#pragma unroll
          for (int q = 0; q < 4; ++q){
            int rg = brow + wr * 64 + m * 16 + qrow + q;
            if (rg < M){
              float v = acc[m][n][q] + bv;
              if (act2) v = (v > 0.f) ? v : expm1f(v);
              if (NCH == 3)
                reinterpret_cast<unsigned char*>(C)[(size_t)rg * HE + pi(cglob)] = f2fp8(v);
              else
                C[(size_t)rg * 512 + cglob] = f2b(v);
            }
          }
        }
      }
    }
    if (a_s){
      const int cin = wc * 64;
      float asv[4], adv[4];
#pragma unroll
      for (int n = 0; n < 4; ++n){
        int cglob = cc * 128 + cin + n * 16 + r15;
        asv[n] = a_s[cglob]; adv[n] = a_d[cglob];
      }
#pragma unroll
      for (int m = 0; m < 4; ++m){
#pragma unroll
        for (int q = 0; q < 4; ++q){
          float ps = acc[m][0][q] * asv[0] + acc[m][1][q] * asv[1]
                   + acc[m][2][q] * asv[2] + acc[m][3][q] * asv[3];
          float pd = acc[m][0][q] * adv[0] + acc[m][1][q] * adv[1]
                   + acc[m][2][q] * adv[2] + acc[m][3][q] * adv[3];
#pragma unroll
          for (int off = 1; off < 16; off <<= 1){
            ps += __shfl_xor(ps, off);
            pd += __shfl_xor(pd, off);
          }
          if (r15 == 0){
            int rowl = wr * 64 + m * 16 + qrow + q;
            sred[wc][rowl] = ps;
            dred[wc][rowl] = pd;
          }
        }
      }
      __syncthreads();
      if (threadIdx.x < 128){
        int rowl = threadIdx.x;
        int rg = brow + rowl;
        if (rg < M){
          als[(size_t)rg * 3 + cc] = sred[0][rowl] + sred[1][rowl];
          ald[(size_t)rg * 3 + cc] = dred[0][rowl] + dred[1][rowl];
        }
      }
    }
  }
  if (FINAL){
    __syncthreads();
    if (threadIdx.x < 128){
      int rg = brow + threadIdx.x;
      if (rg < M){
        float z = zsum[0][threadIdx.x] + zsum[1][threadIdx.x] + b2s[0];
        outp[rg] = 1.f / (1.f + __expf(-z));
      }
    }
  }
}

// ---------------- GAT aggregation (1 wave/node) + inline self-loop, h in fp8 ----
// h row = 384 bytes (pi layout); lane owns 6 bytes = 3 head-pairs at lane*6.
__global__ __launch_bounds__(256) void k_agg(const unsigned char* __restrict__ h,
                                             const float* __restrict__ als,
                                             const float* __restrict__ ald,
                                             const int* __restrict__ rs, const int* __restrict__ cntp,
                                             const int* __restrict__ esrc,
                                             const float* __restrict__ bias,
                                             unsigned short* __restrict__ out, int Nn){
  __shared__ float exs[4][EXCAP * 3];      // 12 KB: per-wave ex cache
  int wave = threadIdx.x >> 6;
  int n = blockIdx.x * 4 + wave;
  int lane = threadIdx.x & 63;
  if (n >= Nn) return;
  int start = rs[n];
  int end = start + cntp[n];
  f32x3 adn = *reinterpret_cast<const f32x3*>(&ald[(size_t)n * 3]);
  f32x3 asn = *reinterpret_cast<const f32x3*>(&als[(size_t)n * 3]);
  float es0 = __expf(lrelu(asn.x + adn.x));   // self-loop term (wave-uniform)
  float es1 = __expf(lrelu(asn.y + adn.y));
  float es2 = __expf(lrelu(asn.z + adn.z));
  float d0 = 0.f, d1 = 0.f, d2 = 0.f;
  for (int i = start + lane; i < end; i += 64){
    int s = esrc[i];
    f32x3 as = *reinterpret_cast<const f32x3*>(&als[(size_t)s * 3]);
    float e0 = __expf(lrelu(as.x + adn.x));
    float e1 = __expf(lrelu(as.y + adn.y));
    float e2 = __expf(lrelu(as.z + adn.z));
    d0 += e0; d1 += e1; d2 += e2;
    int j = i - start;
    if (j < EXCAP){
      exs[wave][j * 3 + 0] = e0;
      exs[wave][j * 3 + 1] = e1;
      exs[wave][j * 3 + 2] = e2;
    }
  }
  for (int off = 32; off; off >>= 1){
    d0 += __shfl_xor(d0, off);
    d1 += __shfl_xor(d1, off);
    d2 += __shfl_xor(d2, off);
  }
  d0 += es0; d1 += es1; d2 += es2;
  float iv[3] = {1.f / (d0 + 1e-16f), 1.f / (d1 + 1e-16f), 1.f / (d2 + 1e-16f)};
  const int l6 = lane * 6;
  float acc[6];
  {
    const unsigned char* hn = h + (size_t)n * HE + l6;
    unsigned u0 = *reinterpret_cast<const unsigned short*>(hn);
    unsigned u1 = *reinterpret_cast<const unsigned short*>(hn + 2);
    unsigned u2 = *reinterpret_cast<const unsigned short*>(hn + 4);
    acc[0] = es0 * fp8f<0>(u0);
    acc[1] = es0 * fp8f<1>(u0);
    acc[2] = es1 * fp8f<0>(u1);
    acc[3] = es1 * fp8f<1>(u1);
    acc[4] = es2 * fp8f<0>(u2);
    acc[5] = es2 * fp8f<1>(u2);
  }
  const float* exw = exs[wave];
  int i = start;
  int nfast = end;
  if (end - start > EXCAP) nfast = start + EXCAP;
  for (; i + 3 < nfast; i += 4){
    unsigned hv[4][3]; f32x3 ev[4];
#pragma unroll
    for (int u = 0; u < 4; ++u){
      int s = esrc[i + u];
      const unsigned char* hs = h + (size_t)s * HE + l6;
      hv[u][0] = *reinterpret_cast<const unsigned short*>(hs);
      hv[u][1] = *reinterpret_cast<const unsigned short*>(hs + 2);
      hv[u][2] = *reinterpret_cast<const unsigned short*>(hs + 4);
      int j = (i + u - start) * 3;
      ev[u].x = exw[j]; ev[u].y = exw[j + 1]; ev[u].z = exw[j + 2];
    }
#pragma unroll
    for (int u = 0; u < 4; ++u){
      acc[0] += ev[u].x * fp8f<0>(hv[u][0]);
      acc[1] += ev[u].x * fp8f<1>(hv[u][0]);
      acc[2] += ev[u].y * fp8f<0>(hv[u][1]);
      acc[3] += ev[u].y * fp8f<1>(hv[u][1]);
      acc[4] += ev[u].z * fp8f<0>(hv[u][2]);
      acc[5] += ev[u].z * fp8f<1>(hv[u][2]);
    }
  }
  for (; i < end; ++i){
    int j = i - start;
    int s = esrc[i];
    float e0, e1, e2;
    if (j < EXCAP){
      e0 = exw[j * 3]; e1 = exw[j * 3 + 1]; e2 = exw[j * 3 + 2];
    } else {
      f32x3 as = *reinterpret_cast<const f32x3*>(&als[(size_t)s * 3]);
      e0 = __expf(lrelu(as.x + adn.x));
      e1 = __expf(lrelu(as.y + adn.y));
      e2 = __expf(lrelu(as.z + adn.z));
    }
    const unsigned char* hs = h + (size_t)s * HE + l6;
    unsigned u0 = *reinterpret_cast<const unsigned short*>(hs);
    unsigned u1 = *reinterpret_cast<const unsigned short*>(hs + 2);
    unsigned u2 = *reinterpret_cast<const unsigned short*>(hs + 4);
    acc[0] += e0 * fp8f<0>(u0);
    acc[1] += e0 * fp8f<1>(u0);
    acc[2] += e1 * fp8f<0>(u1);
    acc[3] += e1 * fp8f<1>(u1);
    acc[4] += e2 * fp8f<0>(u2);
    acc[5] += e2 * fp8f<1>(u2);
  }
  unsigned ov[3];
#pragma unroll
  for (int hh = 0; hh < 3; ++hh){
    int ch = 128 * hh + 2 * lane;
    float v0 = acc[2 * hh] * iv[hh] + bias[ch];
    float v1 = acc[2 * hh + 1] * iv[hh] + bias[ch + 1];
    v0 = (v0 > 0.f) ? v0 : expm1f(v0);
    v1 = (v1 > 0.f) ? v1 : expm1f(v1);
    ov[hh] = (unsigned)f2b(v0) | ((unsigned)f2b(v1) << 16);
  }
  // Q stays bf16 pi layout: lane's 3 dwords at dword offset lane*3
  unsigned* orow = reinterpret_cast<unsigned*>(out + (size_t)n * HE) + lane * 3;
  orow[0] = ov[0]; orow[1] = ov[1]; orow[2] = ov[2];
}

extern "C" void kernel_launch(void* const* d_in, const int* in_sizes, int n_in,
                              void* d_out, int out_size, void* d_ws, size_t ws_size,
                              hipStream_t stream){
  const float* x   = (const float*)d_in[0];
  const int*   ei  = (const int*)d_in[1];
  const int N = in_sizes[0] / F_IN;
  const int E = in_sizes[1] / 2;
  const float* W[3]  = {(const float*)d_in[2], (const float*)d_in[6], (const float*)d_in[10]};
  const float* AS[3] = {(const float*)d_in[3], (const float*)d_in[7], (const float*)d_in[11]};
  const float* AD[3] = {(const float*)d_in[4], (const float*)d_in[8], (const float*)d_in[12]};
  const float* BB[3] = {(const float*)d_in[5], (const float*)d_in[9], (const float*)d_in[13]};
  const float* WH[3] = {(const float*)d_in[14], (const float*)d_in[16], (const float*)d_in[18]};
  const float* BH[3] = {(const float*)d_in[15], (const float*)d_in[17], (const float*)d_in[19]};
  const float* Wl1 = (const float*)d_in[20];
  const float* bl1 = (const float*)d_in[21];
  const float* Wl2 = (const float*)d_in[22];
  const float* bl2 = (const float*)d_in[23];
  float* out = (float*)d_out;

  // ---- workspace layout ----
  char* ws = (char*)d_ws;
  size_t off = 0;
  auto alloc = [&](size_t bytes) -> char* {
    char* p = ws + off;
    off = (off + bytes + 255) & ~(size_t)255;
    return p;
  };
  int*   row_start = (int*)alloc((size_t)N * 4);
  int*   cnt       = (int*)alloc((size_t)N * 4);
  int*   esrc      = (int*)alloc((size_t)E * 4);
  int*   rank      = (int*)alloc((size_t)E * 4);
  int*   cursor    = (int*)alloc(256);
  float* als       = (float*)alloc((size_t)N * 3 * 4);
  float* ald       = (float*)alloc((size_t)N * 3 * 4);
  unsigned short* xb = (unsigned short*)alloc((size_t)N * F_IN * 2);   // x bf16
  unsigned char*  P  = (unsigned char*)alloc((size_t)N * HE);          // h fp8 (pi layout)
  unsigned short* Q  = (unsigned short*)alloc((size_t)N * HE * 2);     // agg out bf16 (pi layout)
  // weight slabs
  unsigned short* W1T  = (unsigned short*)alloc((size_t)F_IN * HE * 2);  // [384,128]
  unsigned short* W2T  = (unsigned short*)alloc((size_t)F_IN * HE * 2);
  unsigned short* W3T  = (unsigned short*)alloc((size_t)F_IN * HE * 2);
  unsigned short* WhPT[3];
  for (int l = 0; l < 3; ++l)
    WhPT[l] = (unsigned short*)alloc((size_t)HE * F_IN * 2);            // [128,384] K pi-permuted
  unsigned short* Wl1T = (unsigned short*)alloc((size_t)F_IN * 512 * 2); // [512,128]

  // ---- single prep dispatch ----
  const int n4 = N * F_IN / 4;
  const int prep_total = n4 + 6 * S1 + S3 + N + 1;
  k_prep<<<(prep_total + 255) / 256, 256, 0, stream>>>(
      x, xb, n4, W[0], W[1], W[2], W1T, W2T, W3T,
      WH[0], WH[1], WH[2], WhPT[0], WhPT[1], WhPT[2], Wl1, Wl1T, cnt, cursor, N);

  // ---- CSR by dst ----
  k_hist<<<2048, 256, 0, stream>>>(ei, E, cnt, rank);
  k_offsets<<<(N + 255) / 256, 256, 0, stream>>>(cnt, row_start, cursor, N);
  k_scatter<<<2048, 256, 0, stream>>>(ei, E, row_start, rank, esrc);

  const int mb = (N + 127) / 128;
  const int nwave = (N + 3) / 4;

  // ---- layer 1: P(fp8) = x@W1 + als/ald; agg ----
  k_mgemm<128, true><<<dim3(mb, 3), 256, 0, stream>>>(xb, W1T, nullptr,
      (unsigned short*)P, AS[0], AD[0], als, ald, N, HE, 0);
  k_agg<<<nwave, 256, 0, stream>>>(P, als, ald, row_start, cnt, esrc, BB[0], Q, N);
  // ---- layer 2: fused (R1 = Q@Wh1+bh1) -> P(fp8) = R1@W2 + als/ald; agg ----
  k_fused<3, false><<<mb, 256, 0, stream>>>(Q, WhPT[0], BH[0], W2T, nullptr,
      (unsigned short*)P, AS[1], AD[1], als, ald, nullptr, nullptr, nullptr, N, 0);
  k_agg<<<nwave, 256, 0, stream>>>(P, als, ald, row_start, cnt, esrc, BB[1], Q, N);
  // ---- layer 3 ----
  k_fused<3, false><<<mb, 256, 0, stream>>>(Q, WhPT[1], BH[1], W3T, nullptr,
      (unsigned short*)P, AS[2], AD[2], als, ald, nullptr, nullptr, nullptr, N, 0);
  k_agg<<<nwave, 256, 0, stream>>>(P, als, ald, row_start, cnt, esrc, BB[2], Q, N);
  // ---- MLP + head fused ----
  k_fused<4, true><<<mb, 256, 0, stream>>>(Q, WhPT[2], BH[2], Wl1T, bl1, nullptr,
      nullptr, nullptr, nullptr, nullptr, Wl2, bl2, out, N, 1);
}

// Round 16
// 517.342 us; speedup vs baseline: 1.1385x; 1.0156x over previous
//
#include <hip/hip_runtime.h>
#include <hip/hip_bf16.h>
#include <cstdint>
#include <cstddef>

// GuidedGNN: 3x GATConv(H=3, EMB=128, concat) + head transforms + MLP head.
// R13: k_agg is VALU-bound (57% VALU, 22% HBM after fp8) -> cut per-edge
// instructions: fp8 rows padded to stride 512 (lane owns 8B aligned -> ONE
// uint2 load/edge instead of 3 ushort loads) + packed cvt_pk_f32_fp8 (3 pk
// cvts instead of 6 scalar). Layout pi8(c) = lane*8 + head*2 + parity.

#define F_IN 128
#define EMB  128
#define NH   3
#define HE   (NH*EMB)   // 384
#define PSTR 512        // fp8 P row stride (bytes): 64 lanes x 8
#define EXCAP 256       // per-wave LDS ex-cache entries (max real deg ~45)

typedef __attribute__((ext_vector_type(8))) short bf16x8;
typedef __attribute__((ext_vector_type(4))) float f32x4;
typedef __attribute__((ext_vector_type(2))) float f32x2;

__device__ __forceinline__ float lrelu(float x){ return x > 0.f ? x : 0.2f * x; }
__device__ __forceinline__ float b2f(unsigned short u){ return __uint_as_float((unsigned)u << 16); }
__device__ __forceinline__ unsigned short f2b(float f){
  __hip_bfloat16 h = __float2bfloat16(f);
  return *reinterpret_cast<unsigned short*>(&h);
}
// fp8 byte position within a PSTR row: lane (w>>1) owns 8 bytes; head pairs packed
__device__ __forceinline__ int pi8(int c){
  int hh = c >> 7, w = c & 127;
  return (w >> 1) * 8 + hh * 2 + (w & 1);
}
__device__ __forceinline__ void gload16(const unsigned short* g, unsigned short* l){
  __builtin_amdgcn_global_load_lds((const __attribute__((address_space(1))) unsigned int*)g,
                                   (__attribute__((address_space(3))) unsigned int*)l, 16, 0, 0);
}

// ---- fp8 e4m3 (OCP on gfx950) helpers ----
#if __has_builtin(__builtin_amdgcn_cvt_pk_fp8_f32)
__device__ __forceinline__ unsigned char f2fp8(float f){
  int r = __builtin_amdgcn_cvt_pk_fp8_f32(f, f, 0, false);
  return (unsigned char)(r & 0xff);
}
#else
__device__ __forceinline__ unsigned char f2fp8(float f){
  float a = fabsf(f);
  unsigned s = (__float_as_uint(f) >> 31) << 7;
  if (a < 7.8125e-3f) return (unsigned char)s;
  a = fminf(a, 448.f);
  unsigned u = __float_as_uint(a);
  int e = (int)(u >> 23) - 127;
  unsigned m = (u >> 20) & 7;
  unsigned rest = u & 0xFFFFF;
  if (rest > 0x80000 || (rest == 0x80000 && (m & 1))){ m++; if (m == 8){ m = 0; e++; } }
  if (e > 8){ e = 8; m = 7; }
  if (e < -6){ e = -6; }
  return (unsigned char)(s | ((unsigned)(e + 7) << 3) | m);
}
#endif
#if __has_builtin(__builtin_amdgcn_cvt_pk_f32_fp8)
template<bool HI>
__device__ __forceinline__ f32x2 fp8pk(unsigned int u){
  return __builtin_amdgcn_cvt_pk_f32_fp8(u, HI);
}
#else
template<int SEL>
__device__ __forceinline__ float fp8f1(unsigned int u){
  unsigned char b = (u >> (8 * SEL)) & 0xff;
  int e = (b >> 3) & 15, m = b & 7;
  float v = (e == 0) ? (float)m * 0.001953125f
                     : (float)(8 + m) * exp2f((float)(e - 10));
  return (b & 0x80) ? -v : v;
}
template<bool HI>
__device__ __forceinline__ f32x2 fp8pk(unsigned int u){
  f32x2 r;
  if (HI){ r[0] = fp8f1<2>(u); r[1] = fp8f1<3>(u); }
  else   { r[0] = fp8f1<0>(u); r[1] = fp8f1<1>(u); }
  return r;
}
#endif

struct f32x3 { float x, y, z; };

// ---------------- combined prep: x->bf16, weight transposes, cnt/cursor zero ----------------
#define S1 49152   // 128*384
#define S3 65536   // 128*512
__global__ void k_prep(const float* __restrict__ x, unsigned short* __restrict__ xb, int n4,
                       const float* __restrict__ W1, const float* __restrict__ W2,
                       const float* __restrict__ W3,
                       unsigned short* __restrict__ W1T, unsigned short* __restrict__ W2T,
                       unsigned short* __restrict__ W3T,
                       const float* __restrict__ Wh1, const float* __restrict__ Wh2,
                       const float* __restrict__ Wh3,
                       unsigned short* __restrict__ Wh1T, unsigned short* __restrict__ Wh2T,
                       unsigned short* __restrict__ Wh3T,
                       const float* __restrict__ Wl1, unsigned short* __restrict__ Wl1T,
                       int* __restrict__ cnt, int* __restrict__ cursor, int Nn){
  int i = blockIdx.x * 256 + threadIdx.x;
  if (i < n4){
    float4 v = reinterpret_cast<const float4*>(x)[i];
    unsigned short o[4] = {f2b(v.x), f2b(v.y), f2b(v.z), f2b(v.w)};
    *reinterpret_cast<uint2*>(&xb[i * 4]) = *reinterpret_cast<uint2*>(o);
    return;
  }
  i -= n4;
  if (i < 3 * S1){  // W1/W2/W3 [128,384] -> [384,128]
    const float* Wsrc = (i < S1) ? W1 : (i < 2 * S1) ? W2 : W3;
    unsigned short* Wdst = (i < S1) ? W1T : (i < 2 * S1) ? W2T : W3T;
    int j = i % S1;
    int r = j / HE, c = j % HE;
    Wdst[(size_t)c * F_IN + r] = f2b(Wsrc[j]);
    return;
  }
  i -= 3 * S1;
  if (i < 3 * S1){  // Wh1/2/3 [384,128] -> [128 cols][384] K pi-permuted (bf16 side keeps old pi)
    const float* Wsrc = (i < S1) ? Wh1 : (i < 2 * S1) ? Wh2 : Wh3;
    unsigned short* Wdst = (i < S1) ? Wh1T : (i < 2 * S1) ? Wh2T : Wh3T;
    int j = i % S1;
    int r = j / F_IN, c = j % F_IN;
    int hh = r >> 7, w = r & 127;
    int pr = (w >> 1) * 6 + hh * 2 + (w & 1);   // Q's bf16 pi layout (unchanged)
    Wdst[(size_t)c * HE + pr] = f2b(Wsrc[j]);
    return;
  }
  i -= 3 * S1;
  if (i < S3){      // Wl1 [128,512] -> [512,128]
    int r = i / 512, c = i % 512;
    Wl1T[(size_t)c * F_IN + r] = f2b(Wl1[i]);
    return;
  }
  i -= S3;
  if (i < Nn){ cnt[i] = 0; return; }
  i -= Nn;
  if (i == 0) cursor[0] = 0;
}

// ---------------- CSR build (real edges only; self-loops handled in k_agg) ----------------
__global__ void k_hist(const int* __restrict__ ei, int E, int* __restrict__ cnt,
                       int* __restrict__ rank){
  for (int i = blockIdx.x * blockDim.x + threadIdx.x; i < E; i += gridDim.x * blockDim.x){
    int d = ei[E + i];
    rank[i] = atomicAdd(&cnt[d], 1);
  }
}

// one-dispatch offsets: wave shfl-scan + global cursor.
__global__ void k_offsets(const int* __restrict__ cnt, int* __restrict__ rs,
                          int* __restrict__ cursor, int Nn){
  int n = blockIdx.x * 256 + threadIdx.x;
  int lane = threadIdx.x & 63;
  int v = (n < Nn) ? cnt[n] : 0;
  int inc = v;
#pragma unroll
  for (int off = 1; off < 64; off <<= 1){
    int t = __shfl_up(inc, off);
    if (lane >= off) inc += t;
  }
  int total = __shfl(inc, 63);
  int base = 0;
  if (lane == 0) base = atomicAdd(cursor, total);
  base = __shfl(base, 0);
  if (n < Nn) rs[n] = base + inc - v;
}

__global__ void k_scatter(const int* __restrict__ ei, int E, const int* __restrict__ rs,
                          const int* __restrict__ rank, int* __restrict__ esrc){
  for (int i = blockIdx.x * blockDim.x + threadIdx.x; i < E; i += gridDim.x * blockDim.x){
    esrc[rs[ei[E + i]] + rank[i]] = ei[i];
  }
}

// ---------------- LDS-pipelined MFMA GEMM (layer-1) ----------------
// PERM: store fp8-e4m3 into pi8 layout, row stride PSTR.
template<int K, bool PERM>
__global__ __launch_bounds__(256, 2) void k_mgemm(const unsigned short* __restrict__ A,
                                                  const unsigned short* __restrict__ BT,
                                                  const float* __restrict__ bias,
                                                  unsigned short* __restrict__ C,
                                                  const float* __restrict__ a_s,
                                                  const float* __restrict__ a_d,
                                                  float* __restrict__ als, float* __restrict__ ald,
                                                  int M, int Ncols, int act){
  __shared__ unsigned short sA[2][8192];   // [buf][128 rows x 64 k] swizzled
  __shared__ unsigned short sB[2][8192];
  const int lane = threadIdx.x & 63;
  const int wave = threadIdx.x >> 6;
  const int brow = blockIdx.x * 128;
  const int bcol = blockIdx.y * 128;
  const int wr = wave >> 1, wc = wave & 1;
  const int r15 = lane & 15;
  const int kg = (lane >> 4) * 8;
  const int row0 = brow + wr * 64;
  const int col0 = bcol + wc * 64;
  f32x4 acc[4][4] = {};

  const int cbase = wave * 64 + lane;
  auto stage = [&](int buf, int kt){
#pragma unroll
    for (int j = 0; j < 4; ++j){
      int c = cbase + j * 256;
      int r = c >> 3;
      int k0 = ((c ^ r) & 7) * 8;
      int ldsoff = (wave * 64 + j * 256) * 8;   // wave-uniform; HW adds lane*16B
      int ra = brow + r; if (ra >= M) ra = M - 1;
      gload16(&A[(size_t)ra * K + kt + k0], &sA[buf][ldsoff]);
      gload16(&BT[(size_t)(bcol + r) * K + kt + k0], &sB[buf][ldsoff]);
    }
  };
  auto compute = [&](int buf){
#pragma unroll
    for (int ks = 0; ks < 2; ++ks){
      bf16x8 a[4], b[4];
#pragma unroll
      for (int m = 0; m < 4; ++m){
        int row = wr * 64 + m * 16 + r15;
        int idx = (row * 64 + ks * 32 + kg) ^ ((row & 7) << 3);
        a[m] = *reinterpret_cast<const bf16x8*>(&sA[buf][idx]);
      }
#pragma unroll
      for (int n = 0; n < 4; ++n){
        int row = wc * 64 + n * 16 + r15;
        int idx = (row * 64 + ks * 32 + kg) ^ ((row & 7) << 3);
        b[n] = *reinterpret_cast<const bf16x8*>(&sB[buf][idx]);
      }
#pragma unroll
      for (int m = 0; m < 4; ++m)
#pragma unroll
        for (int n = 0; n < 4; ++n)
          acc[m][n] = __builtin_amdgcn_mfma_f32_16x16x32_bf16(a[m], b[n], acc[m][n], 0, 0, 0);
    }
  };

  constexpr int NK = K / 64;
  stage(0, 0);
  int cur = 0;
#pragma unroll
  for (int t = 0; t < NK; ++t){
    __syncthreads();
    if (t + 1 < NK) stage(cur ^ 1, (t + 1) * 64);
    compute(cur);
    cur ^= 1;
  }

#pragma unroll
  for (int m = 0; m < 4; ++m){
#pragma unroll
    for (int n = 0; n < 4; ++n){
      int c = col0 + n * 16 + r15;
      float bsv = bias ? bias[c] : 0.f;
#pragma unroll
      for (int q = 0; q < 4; ++q){
        int r = row0 + m * 16 + (lane >> 4) * 4 + q;
        if (r < M){
          float v = acc[m][n][q] + bsv;
          if (act) v = (v > 0.f) ? v : expm1f(v);
          if (PERM) reinterpret_cast<unsigned char*>(C)[(size_t)r * PSTR + pi8(c)] = f2fp8(v);
          else C[(size_t)r * Ncols + c] = f2b(v);
        }
      }
    }
  }
  if (a_s){
    __syncthreads();
    float* sred = reinterpret_cast<float*>(&sA[0][0]);   // [2][128]
    float* dred = sred + 256;
    const int head = blockIdx.y;
    const int cin = wc * 64;
    float asv[4], adv[4];
#pragma unroll
    for (int n = 0; n < 4; ++n){
      int c = head * EMB + cin + n * 16 + r15;
      asv[n] = a_s[c]; adv[n] = a_d[c];
    }
#pragma unroll
    for (int m = 0; m < 4; ++m){
#pragma unroll
      for (int q = 0; q < 4; ++q){
        float ps = acc[m][0][q] * asv[0] + acc[m][1][q] * asv[1]
                 + acc[m][2][q] * asv[2] + acc[m][3][q] * asv[3];
        float pd = acc[m][0][q] * adv[0] + acc[m][1][q] * adv[1]
                 + acc[m][2][q] * adv[2] + acc[m][3][q] * adv[3];
#pragma unroll
        for (int off = 1; off < 16; off <<= 1){
          ps += __shfl_xor(ps, off);
          pd += __shfl_xor(pd, off);
        }
        if (r15 == 0){
          int rowl = wr * 64 + m * 16 + (lane >> 4) * 4 + q;
          sred[wc * 128 + rowl] = ps;
          dred[wc * 128 + rowl] = pd;
        }
      }
    }
    __syncthreads();
    if (threadIdx.x < 128){
      int rowl = threadIdx.x;
      int r = brow + rowl;
      if (r < M){
        als[(size_t)r * 3 + head] = sred[rowl] + sred[128 + rowl];
        ald[(size_t)r * 3 + head] = dred[rowl] + dred[128 + rowl];
      }
    }
  }
}

// ---------------- fused dependent GEMM ----------------
// T = A@B1^T + bias1 (K=384, LDS dbuf); then per 128-col chunk C = T@B2_chunk^T.
// NCH==3: fp8-pi8 store + als/ald epilogue. FINAL: dot with w2 -> sigmoid out.
template<int NCH, bool FINAL>
__global__ __launch_bounds__(256, 2) void k_fused(const unsigned short* __restrict__ A,
                                                  const unsigned short* __restrict__ B1,
                                                  const float* __restrict__ bias1,
                                                  const unsigned short* __restrict__ B2,
                                                  const float* __restrict__ bias2,
                                                  unsigned short* __restrict__ C,
                                                  const float* __restrict__ a_s,
                                                  const float* __restrict__ a_d,
                                                  float* __restrict__ als, float* __restrict__ ald,
                                                  const float* __restrict__ w2,
                                                  const float* __restrict__ b2s,
                                                  float* __restrict__ outp,
                                                  int M, int act2){
  __shared__ unsigned short sA[2][8192];   // stage-1 A dbuf; then T[128][128] swizzled
  __shared__ unsigned short sB[2][8192];   // stage-1 B dbuf; then B2 chunk (32KB)
  __shared__ float sred[2][128];
  __shared__ float dred[2][128];
  __shared__ float zsum[2][128];
  const int lane = threadIdx.x & 63;
  const int wave = threadIdx.x >> 6;
  const int brow = blockIdx.x * 128;
  const int wr = wave >> 1, wc = wave & 1;
  const int r15 = lane & 15;
  const int kg = (lane >> 4) * 8;
  const int qrow = (lane >> 4) * 4;
  f32x4 acc[4][4] = {};
  const int cbase = wave * 64 + lane;
  unsigned short* Bs = &sB[0][0];

  if (FINAL && threadIdx.x < 128){ zsum[0][threadIdx.x] = 0.f; zsum[1][threadIdx.x] = 0.f; }

  auto stageB2 = [&](int cc, int jlo, int jhi){
    for (int j = jlo; j < jhi; ++j){
      int c = cbase + j * 256;     // 128 rows x 16 chunks (CPR=16)
      int r = c >> 4;
      int cr = c & 15;
      int k0 = ((cr & 8) | ((cr ^ r) & 7)) * 8;
      int ldsoff = (wave * 64 + j * 256) * 8;
      gload16(&B2[(size_t)(cc * 128 + r) * 128 + k0], &Bs[ldsoff]);
    }
  };

  // ---- stage 1: T = A(pi)@B1^T, K=384, BK=64 double-buffered ----
  auto stage1 = [&](int buf, int kt){
#pragma unroll
    for (int j = 0; j < 4; ++j){
      int c = cbase + j * 256;
      int r = c >> 3;
      int k0 = ((c ^ r) & 7) * 8;
      int ldsoff = (wave * 64 + j * 256) * 8;
      int ra = brow + r; if (ra >= M) ra = M - 1;
      gload16(&A[(size_t)ra * HE + kt + k0], &sA[buf][ldsoff]);
      gload16(&B1[(size_t)r * HE + kt + k0], &sB[buf][ldsoff]);
    }
  };
  stage1(0, 0);
  int cur = 0;
#pragma unroll
  for (int t = 0; t < 6; ++t){
    __syncthreads();
    if (t + 1 < 6) stage1(cur ^ 1, (t + 1) * 64);
    else stageB2(0, 0, 4);   // rows 0-63 of chunk0 -> sB[0] (dead this step)
#pragma unroll
    for (int ks = 0; ks < 2; ++ks){
      bf16x8 a[4], b[4];
#pragma unroll
      for (int m = 0; m < 4; ++m){
        int row = wr * 64 + m * 16 + r15;
        int idx = (row * 64 + ks * 32 + kg) ^ ((row & 7) << 3);
        a[m] = *reinterpret_cast<const bf16x8*>(&sA[cur][idx]);
      }
#pragma unroll
      for (int n = 0; n < 4; ++n){
        int row = wc * 64 + n * 16 + r15;
        int idx = (row * 64 + ks * 32 + kg) ^ ((row & 7) << 3);
        b[n] = *reinterpret_cast<const bf16x8*>(&sB[cur][idx]);
      }
#pragma unroll
      for (int m = 0; m < 4; ++m)
#pragma unroll
        for (int n = 0; n < 4; ++n)
          acc[m][n] = __builtin_amdgcn_mfma_f32_16x16x32_bf16(a[m], b[n], acc[m][n], 0, 0, 0);
    }
    cur ^= 1;
  }
  __syncthreads();   // all stage-1 LDS reads done (+ chunk0 first-half landed)
  unsigned short* T = &sA[0][0];
#pragma unroll
  for (int m = 0; m < 4; ++m){
#pragma unroll
    for (int n = 0; n < 4; ++n){
      int col = wc * 64 + n * 16 + r15;
      float bv = bias1[col];
#pragma unroll
      for (int q = 0; q < 4; ++q){
        int row = wr * 64 + m * 16 + qrow + q;
        T[(row * 128 + col) ^ ((row & 7) << 3)] = f2b(acc[m][n][q] + bv);
      }
    }
  }

  // ---- stage 2: per 128-col chunk ----
#pragma unroll
  for (int cc = 0; cc < NCH; ++cc){
    if (cc == 0){
      __syncthreads();           // T visible; stage-1 sB[1] reads done
      stageB2(0, 4, 8);          // rows 64-127 of chunk0 -> sB[1]
    } else {
      __syncthreads();           // prev chunk's Bs reads done
      stageB2(cc, 0, 8);
    }
    __syncthreads();             // staged chunk visible
#pragma unroll
    for (int m = 0; m < 4; ++m)
#pragma unroll
      for (int n = 0; n < 4; ++n)
        acc[m][n] = (f32x4){0.f, 0.f, 0.f, 0.f};
#pragma unroll
    for (int ks = 0; ks < 4; ++ks){
      bf16x8 a[4], b[4];
#pragma unroll
      for (int m = 0; m < 4; ++m){
        int row = wr * 64 + m * 16 + r15;
        int idx = (row * 128 + ks * 32 + kg) ^ ((row & 7) << 3);
        a[m] = *reinterpret_cast<const bf16x8*>(&T[idx]);
      }
#pragma unroll
      for (int n = 0; n < 4; ++n){
        int row = wc * 64 + n * 16 + r15;
        int idx = (row * 128 + ks * 32 + kg) ^ ((row & 7) << 3);
        b[n] = *reinterpret_cast<const bf16x8*>(&Bs[idx]);
      }
#pragma unroll
      for (int m = 0; m < 4; ++m)
#pragma unroll
        for (int n = 0; n < 4; ++n)
          acc[m][n] = __builtin_amdgcn_mfma_f32_16x16x32_bf16(a[m], b[n], acc[m][n], 0, 0, 0);
    }
    if (FINAL){
      float w2v[4];
#pragma unroll
      for (int n = 0; n < 4; ++n)
        w2v[n] = w2[cc * 128 + wc * 64 + n * 16 + r15];
#pragma unroll
      for (int m = 0; m < 4; ++m){
#pragma unroll
        for (int q = 0; q < 4; ++q){
          float p = 0.f;
#pragma unroll
          for (int n = 0; n < 4; ++n){
            float v = acc[m][n][q] + bias2[cc * 128 + wc * 64 + n * 16 + r15];
            v = (v > 0.f) ? v : expm1f(v);
            p += v * w2v[n];
          }
#pragma unroll
          for (int off = 1; off < 16; off <<= 1) p += __shfl_xor(p, off);
          if (r15 == 0) zsum[wc][wr * 64 + m * 16 + qrow + q] += p;
        }
      }
    } else {
#pragma unroll
      for (int m = 0; m < 4; ++m){
#pragma unroll
        for (int n = 0; n < 4; ++n){
          int cglob = cc * 128 + wc * 64 + n * 16 + r15;
          float bv = bias2 ? bias2[cglob] : 0.f;
#pragma unroll
          for (int q = 0; q < 4; ++q){
            int rg = brow + wr * 64 + m * 16 + qrow + q;
            if (rg < M){
              float v = acc[m][n][q] + bv;
              if (act2) v = (v > 0.f) ? v : expm1f(v);
              if (NCH == 3)
                reinterpret_cast<unsigned char*>(C)[(size_t)rg * PSTR + pi8(cglob)] = f2fp8(v);
              else
                C[(size_t)rg * 512 + cglob] = f2b(v);
            }
          }
        }
      }
    }
    if (a_s){
      const int cin = wc * 64;
      float asv[4], adv[4];
#pragma unroll
      for (int n = 0; n < 4; ++n){
        int cglob = cc * 128 + cin + n * 16 + r15;
        asv[n] = a_s[cglob]; adv[n] = a_d[cglob];
      }
#pragma unroll
      for (int m = 0; m < 4; ++m){
#pragma unroll
        for (int q = 0; q < 4; ++q){
          float ps = acc[m][0][q] * asv[0] + acc[m][1][q] * asv[1]
                   + acc[m][2][q] * asv[2] + acc[m][3][q] * asv[3];
          float pd = acc[m][0][q] * adv[0] + acc[m][1][q] * adv[1]
                   + acc[m][2][q] * adv[2] + acc[m][3][q] * adv[3];
#pragma unroll
          for (int off = 1; off < 16; off <<= 1){
            ps += __shfl_xor(ps, off);
            pd += __shfl_xor(pd, off);
          }
          if (r15 == 0){
            int rowl = wr * 64 + m * 16 + qrow + q;
            sred[wc][rowl] = ps;
            dred[wc][rowl] = pd;
          }
        }
      }
      __syncthreads();
      if (threadIdx.x < 128){
        int rowl = threadIdx.x;
        int rg = brow + rowl;
        if (rg < M){
          als[(size_t)rg * 3 + cc] = sred[0][rowl] + sred[1][rowl];
          ald[(size_t)rg * 3 + cc] = dred[0][rowl] + dred[1][rowl];
        }
      }
    }
  }
  if (FINAL){
    __syncthreads();
    if (threadIdx.x < 128){
      int rg = brow + threadIdx.x;
      if (rg < M){
        float z = zsum[0][threadIdx.x] + zsum[1][threadIdx.x] + b2s[0];
        outp[rg] = 1.f / (1.f + __expf(-z));
      }
    }
  }
}

// ---------------- GAT aggregation (1 wave/node) + inline self-loop, h fp8 stride-512 ----
// lane owns 8 bytes at lane*8 (6 fp8 channels + 2 pad) -> ONE uint2 load/edge,
// 3 packed cvts. Q output stays bf16 pi layout (dword lane*3).
__global__ __launch_bounds__(256) void k_agg(const unsigned char* __restrict__ h,
                                             const float* __restrict__ als,
                                             const float* __restrict__ ald,
                                             const int* __restrict__ rs, const int* __restrict__ cntp,
                                             const int* __restrict__ esrc,
                                             const float* __restrict__ bias,
                                             unsigned short* __restrict__ out, int Nn){
  __shared__ float exs[4][EXCAP * 3];      // 12 KB: per-wave ex cache
  int wave = threadIdx.x >> 6;
  int n = blockIdx.x * 4 + wave;
  int lane = threadIdx.x & 63;
  if (n >= Nn) return;
  int start = rs[n];
  int end = start + cntp[n];
  f32x3 adn = *reinterpret_cast<const f32x3*>(&ald[(size_t)n * 3]);
  f32x3 asn = *reinterpret_cast<const f32x3*>(&als[(size_t)n * 3]);
  float es0 = __expf(lrelu(asn.x + adn.x));   // self-loop term (wave-uniform)
  float es1 = __expf(lrelu(asn.y + adn.y));
  float es2 = __expf(lrelu(asn.z + adn.z));
  float d0 = 0.f, d1 = 0.f, d2 = 0.f;
  for (int i = start + lane; i < end; i += 64){
    int s = esrc[i];
    f32x3 as = *reinterpret_cast<const f32x3*>(&als[(size_t)s * 3]);
    float e0 = __expf(lrelu(as.x + adn.x));
    float e1 = __expf(lrelu(as.y + adn.y));
    float e2 = __expf(lrelu(as.z + adn.z));
    d0 += e0; d1 += e1; d2 += e2;
    int j = i - start;
    if (j < EXCAP){
      exs[wave][j * 3 + 0] = e0;
      exs[wave][j * 3 + 1] = e1;
      exs[wave][j * 3 + 2] = e2;
    }
  }
  for (int off = 32; off; off >>= 1){
    d0 += __shfl_xor(d0, off);
    d1 += __shfl_xor(d1, off);
    d2 += __shfl_xor(d2, off);
  }
  d0 += es0; d1 += es1; d2 += es2;
  float iv[3] = {1.f / (d0 + 1e-16f), 1.f / (d1 + 1e-16f), 1.f / (d2 + 1e-16f)};
  const int l8 = lane * 8;
  float acc[6];
  {
    uint2 v = *reinterpret_cast<const uint2*>(h + (size_t)n * PSTR + l8);
    f32x2 p0 = fp8pk<false>(v.x);
    f32x2 p1 = fp8pk<true>(v.x);
    f32x2 p2 = fp8pk<false>(v.y);
    acc[0] = es0 * p0[0]; acc[1] = es0 * p0[1];
    acc[2] = es1 * p1[0]; acc[3] = es1 * p1[1];
    acc[4] = es2 * p2[0]; acc[5] = es2 * p2[1];
  }
  const float* exw = exs[wave];
  int i = start;
  int nfast = end;
  if (end - start > EXCAP) nfast = start + EXCAP;
  for (; i + 3 < nfast; i += 4){
    uint2 hv[4]; f32x3 ev[4];
#pragma unroll
    for (int u = 0; u < 4; ++u){
      int s = esrc[i + u];
      hv[u] = *reinterpret_cast<const uint2*>(h + (size_t)s * PSTR + l8);
      int j = (i + u - start) * 3;
      ev[u].x = exw[j]; ev[u].y = exw[j + 1]; ev[u].z = exw[j + 2];
    }
#pragma unroll
    for (int u = 0; u < 4; ++u){
      f32x2 p0 = fp8pk<false>(hv[u].x);
      f32x2 p1 = fp8pk<true>(hv[u].x);
      f32x2 p2 = fp8pk<false>(hv[u].y);
      acc[0] += ev[u].x * p0[0]; acc[1] += ev[u].x * p0[1];
      acc[2] += ev[u].y * p1[0]; acc[3] += ev[u].y * p1[1];
      acc[4] += ev[u].z * p2[0]; acc[5] += ev[u].z * p2[1];
    }
  }
  for (; i < end; ++i){
    int j = i - start;
    int s = esrc[i];
    float e0, e1, e2;
    if (j < EXCAP){
      e0 = exw[j * 3]; e1 = exw[j * 3 + 1]; e2 = exw[j * 3 + 2];
    } else {
      f32x3 as = *reinterpret_cast<const f32x3*>(&als[(size_t)s * 3]);
      e0 = __expf(lrelu(as.x + adn.x));
      e1 = __expf(lrelu(as.y + adn.y));
      e2 = __expf(lrelu(as.z + adn.z));
    }
    uint2 v = *reinterpret_cast<const uint2*>(h + (size_t)s * PSTR + l8);
    f32x2 p0 = fp8pk<false>(v.x);
    f32x2 p1 = fp8pk<true>(v.x);
    f32x2 p2 = fp8pk<false>(v.y);
    acc[0] += e0 * p0[0]; acc[1] += e0 * p0[1];
    acc[2] += e1 * p1[0]; acc[3] += e1 * p1[1];
    acc[4] += e2 * p2[0]; acc[5] += e2 * p2[1];
  }
  unsigned ov[3];
#pragma unroll
  for (int hh = 0; hh < 3; ++hh){
    int ch = 128 * hh + 2 * lane;
    float v0 = acc[2 * hh] * iv[hh] + bias[ch];
    float v1 = acc[2 * hh + 1] * iv[hh] + bias[ch + 1];
    v0 = (v0 > 0.f) ? v0 : expm1f(v0);
    v1 = (v1 > 0.f) ? v1 : expm1f(v1);
    ov[hh] = (unsigned)f2b(v0) | ((unsigned)f2b(v1) << 16);
  }
  // Q stays bf16 pi layout: lane's 3 dwords at dword offset lane*3
  unsigned* orow = reinterpret_cast<unsigned*>(out + (size_t)n * HE) + lane * 3;
  orow[0] = ov[0]; orow[1] = ov[1]; orow[2] = ov[2];
}

extern "C" void kernel_launch(void* const* d_in, const int* in_sizes, int n_in,
                              void* d_out, int out_size, void* d_ws, size_t ws_size,
                              hipStream_t stream){
  const float* x   = (const float*)d_in[0];
  const int*   ei  = (const int*)d_in[1];
  const int N = in_sizes[0] / F_IN;
  const int E = in_sizes[1] / 2;
  const float* W[3]  = {(const float*)d_in[2], (const float*)d_in[6], (const float*)d_in[10]};
  const float* AS[3] = {(const float*)d_in[3], (const float*)d_in[7], (const float*)d_in[11]};
  const float* AD[3] = {(const float*)d_in[4], (const float*)d_in[8], (const float*)d_in[12]};
  const float* BB[3] = {(const float*)d_in[5], (const float*)d_in[9], (const float*)d_in[13]};
  const float* WH[3] = {(const float*)d_in[14], (const float*)d_in[16], (const float*)d_in[18]};
  const float* BH[3] = {(const float*)d_in[15], (const float*)d_in[17], (const float*)d_in[19]};
  const float* Wl1 = (const float*)d_in[20];
  const float* bl1 = (const float*)d_in[21];
  const float* Wl2 = (const float*)d_in[22];
  const float* bl2 = (const float*)d_in[23];
  float* out = (float*)d_out;

  // ---- workspace layout ----
  char* ws = (char*)d_ws;
  size_t off = 0;
  auto alloc = [&](size_t bytes) -> char* {
    char* p = ws + off;
    off = (off + bytes + 255) & ~(size_t)255;
    return p;
  };
  int*   row_start = (int*)alloc((size_t)N * 4);
  int*   cnt       = (int*)alloc((size_t)N * 4);
  int*   esrc      = (int*)alloc((size_t)E * 4);
  int*   rank      = (int*)alloc((size_t)E * 4);
  int*   cursor    = (int*)alloc(256);
  float* als       = (float*)alloc((size_t)N * 3 * 4);
  float* ald       = (float*)alloc((size_t)N * 3 * 4);
  unsigned short* xb = (unsigned short*)alloc((size_t)N * F_IN * 2);   // x bf16
  unsigned char*  P  = (unsigned char*)alloc((size_t)N * PSTR);        // h fp8 (pi8, stride 512)
  unsigned short* Q  = (unsigned short*)alloc((size_t)N * HE * 2);     // agg out bf16 (pi layout)
  // weight slabs
  unsigned short* W1T  = (unsigned short*)alloc((size_t)F_IN * HE * 2);  // [384,128]
  unsigned short* W2T  = (unsigned short*)alloc((size_t)F_IN * HE * 2);
  unsigned short* W3T  = (unsigned short*)alloc((size_t)F_IN * HE * 2);
  unsigned short* WhPT[3];
  for (int l = 0; l < 3; ++l)
    WhPT[l] = (unsigned short*)alloc((size_t)HE * F_IN * 2);            // [128,384] K pi-permuted
  unsigned short* Wl1T = (unsigned short*)alloc((size_t)F_IN * 512 * 2); // [512,128]

  // ---- single prep dispatch ----
  const int n4 = N * F_IN / 4;
  const int prep_total = n4 + 6 * S1 + S3 + N + 1;
  k_prep<<<(prep_total + 255) / 256, 256, 0, stream>>>(
      x, xb, n4, W[0], W[1], W[2], W1T, W2T, W3T,
      WH[0], WH[1], WH[2], WhPT[0], WhPT[1], WhPT[2], Wl1, Wl1T, cnt, cursor, N);

  // ---- CSR by dst ----
  k_hist<<<2048, 256, 0, stream>>>(ei, E, cnt, rank);
  k_offsets<<<(N + 255) / 256, 256, 0, stream>>>(cnt, row_start, cursor, N);
  k_scatter<<<2048, 256, 0, stream>>>(ei, E, row_start, rank, esrc);

  const int mb = (N + 127) / 128;
  const int nwave = (N + 3) / 4;

  // ---- layer 1: P(fp8) = x@W1 + als/ald; agg ----
  k_mgemm<128, true><<<dim3(mb, 3), 256, 0, stream>>>(xb, W1T, nullptr,
      (unsigned short*)P, AS[0], AD[0], als, ald, N, HE, 0);
  k_agg<<<nwave, 256, 0, stream>>>(P, als, ald, row_start, cnt, esrc, BB[0], Q, N);
  // ---- layer 2: fused (R1 = Q@Wh1+bh1) -> P(fp8) = R1@W2 + als/ald; agg ----
  k_fused<3, false><<<mb, 256, 0, stream>>>(Q, WhPT[0], BH[0], W2T, nullptr,
      (unsigned short*)P, AS[1], AD[1], als, ald, nullptr, nullptr, nullptr, N, 0);
  k_agg<<<nwave, 256, 0, stream>>>(P, als, ald, row_start, cnt, esrc, BB[1], Q, N);
  // ---- layer 3 ----
  k_fused<3, false><<<mb, 256, 0, stream>>>(Q, WhPT[1], BH[1], W3T, nullptr,
      (unsigned short*)P, AS[2], AD[2], als, ald, nullptr, nullptr, nullptr, N, 0);
  k_agg<<<nwave, 256, 0, stream>>>(P, als, ald, row_start, cnt, esrc, BB[2], Q, N);
  // ---- MLP + head fused ----
  k_fused<4, true><<<mb, 256, 0, stream>>>(Q, WhPT[2], BH[2], Wl1T, bl1, nullptr,
      nullptr, nullptr, nullptr, nullptr, Wl2, bl2, out, N, 1);
}

// Round 17
// 497.470 us; speedup vs baseline: 1.1840x; 1.0399x over previous
//
#include <hip/hip_runtime.h>
#include <hip/hip_bf16.h>
#include <cstdint>
#include <cstddef>

// GuidedGNN: 3x GATConv(H=3, EMB=128, concat) + head transforms + MLP head.
// R14: k_agg register-resident edge metadata -- pass A keeps esrc + ex of the
// first 64 edges in registers; pass B gets them via __shfl (j wave-uniform).
// Kills per-edge esrc VMEM load, all ex LDS traffic, and the 12KB LDS block.
// deg>64 tail (never taken on this graph: max deg ~45) recomputes inline.

#define F_IN 128
#define EMB  128
#define NH   3
#define HE   (NH*EMB)   // 384
#define PSTR 512        // fp8 P row stride (bytes): 64 lanes x 8

typedef __attribute__((ext_vector_type(8))) short bf16x8;
typedef __attribute__((ext_vector_type(4))) float f32x4;
typedef __attribute__((ext_vector_type(2))) float f32x2;

__device__ __forceinline__ float lrelu(float x){ return x > 0.f ? x : 0.2f * x; }
__device__ __forceinline__ float b2f(unsigned short u){ return __uint_as_float((unsigned)u << 16); }
__device__ __forceinline__ unsigned short f2b(float f){
  __hip_bfloat16 h = __float2bfloat16(f);
  return *reinterpret_cast<unsigned short*>(&h);
}
// fp8 byte position within a PSTR row: lane (w>>1) owns 8 bytes; head pairs packed
__device__ __forceinline__ int pi8(int c){
  int hh = c >> 7, w = c & 127;
  return (w >> 1) * 8 + hh * 2 + (w & 1);
}
__device__ __forceinline__ void gload16(const unsigned short* g, unsigned short* l){
  __builtin_amdgcn_global_load_lds((const __attribute__((address_space(1))) unsigned int*)g,
                                   (__attribute__((address_space(3))) unsigned int*)l, 16, 0, 0);
}

// ---- fp8 e4m3 (OCP on gfx950) helpers ----
#if __has_builtin(__builtin_amdgcn_cvt_pk_fp8_f32)
__device__ __forceinline__ unsigned char f2fp8(float f){
  int r = __builtin_amdgcn_cvt_pk_fp8_f32(f, f, 0, false);
  return (unsigned char)(r & 0xff);
}
#else
__device__ __forceinline__ unsigned char f2fp8(float f){
  float a = fabsf(f);
  unsigned s = (__float_as_uint(f) >> 31) << 7;
  if (a < 7.8125e-3f) return (unsigned char)s;
  a = fminf(a, 448.f);
  unsigned u = __float_as_uint(a);
  int e = (int)(u >> 23) - 127;
  unsigned m = (u >> 20) & 7;
  unsigned rest = u & 0xFFFFF;
  if (rest > 0x80000 || (rest == 0x80000 && (m & 1))){ m++; if (m == 8){ m = 0; e++; } }
  if (e > 8){ e = 8; m = 7; }
  if (e < -6){ e = -6; }
  return (unsigned char)(s | ((unsigned)(e + 7) << 3) | m);
}
#endif
#if __has_builtin(__builtin_amdgcn_cvt_pk_f32_fp8)
template<bool HI>
__device__ __forceinline__ f32x2 fp8pk(unsigned int u){
  return __builtin_amdgcn_cvt_pk_f32_fp8(u, HI);
}
#else
template<int SEL>
__device__ __forceinline__ float fp8f1(unsigned int u){
  unsigned char b = (u >> (8 * SEL)) & 0xff;
  int e = (b >> 3) & 15, m = b & 7;
  float v = (e == 0) ? (float)m * 0.001953125f
                     : (float)(8 + m) * exp2f((float)(e - 10));
  return (b & 0x80) ? -v : v;
}
template<bool HI>
__device__ __forceinline__ f32x2 fp8pk(unsigned int u){
  f32x2 r;
  if (HI){ r[0] = fp8f1<2>(u); r[1] = fp8f1<3>(u); }
  else   { r[0] = fp8f1<0>(u); r[1] = fp8f1<1>(u); }
  return r;
}
#endif

struct f32x3 { float x, y, z; };

// ---------------- combined prep: x->bf16, weight transposes, cnt/cursor zero ----------------
#define S1 49152   // 128*384
#define S3 65536   // 128*512
__global__ void k_prep(const float* __restrict__ x, unsigned short* __restrict__ xb, int n4,
                       const float* __restrict__ W1, const float* __restrict__ W2,
                       const float* __restrict__ W3,
                       unsigned short* __restrict__ W1T, unsigned short* __restrict__ W2T,
                       unsigned short* __restrict__ W3T,
                       const float* __restrict__ Wh1, const float* __restrict__ Wh2,
                       const float* __restrict__ Wh3,
                       unsigned short* __restrict__ Wh1T, unsigned short* __restrict__ Wh2T,
                       unsigned short* __restrict__ Wh3T,
                       const float* __restrict__ Wl1, unsigned short* __restrict__ Wl1T,
                       int* __restrict__ cnt, int* __restrict__ cursor, int Nn){
  int i = blockIdx.x * 256 + threadIdx.x;
  if (i < n4){
    float4 v = reinterpret_cast<const float4*>(x)[i];
    unsigned short o[4] = {f2b(v.x), f2b(v.y), f2b(v.z), f2b(v.w)};
    *reinterpret_cast<uint2*>(&xb[i * 4]) = *reinterpret_cast<uint2*>(o);
    return;
  }
  i -= n4;
  if (i < 3 * S1){  // W1/W2/W3 [128,384] -> [384,128]
    const float* Wsrc = (i < S1) ? W1 : (i < 2 * S1) ? W2 : W3;
    unsigned short* Wdst = (i < S1) ? W1T : (i < 2 * S1) ? W2T : W3T;
    int j = i % S1;
    int r = j / HE, c = j % HE;
    Wdst[(size_t)c * F_IN + r] = f2b(Wsrc[j]);
    return;
  }
  i -= 3 * S1;
  if (i < 3 * S1){  // Wh1/2/3 [384,128] -> [128 cols][384] K pi-permuted (bf16 Q layout)
    const float* Wsrc = (i < S1) ? Wh1 : (i < 2 * S1) ? Wh2 : Wh3;
    unsigned short* Wdst = (i < S1) ? Wh1T : (i < 2 * S1) ? Wh2T : Wh3T;
    int j = i % S1;
    int r = j / F_IN, c = j % F_IN;
    int hh = r >> 7, w = r & 127;
    int pr = (w >> 1) * 6 + hh * 2 + (w & 1);   // Q's bf16 pi layout (unchanged)
    Wdst[(size_t)c * HE + pr] = f2b(Wsrc[j]);
    return;
  }
  i -= 3 * S1;
  if (i < S3){      // Wl1 [128,512] -> [512,128]
    int r = i / 512, c = i % 512;
    Wl1T[(size_t)c * F_IN + r] = f2b(Wl1[i]);
    return;
  }
  i -= S3;
  if (i < Nn){ cnt[i] = 0; return; }
  i -= Nn;
  if (i == 0) cursor[0] = 0;
}

// ---------------- CSR build (real edges only; self-loops handled in k_agg) ----------------
__global__ void k_hist(const int* __restrict__ ei, int E, int* __restrict__ cnt,
                       int* __restrict__ rank){
  for (int i = blockIdx.x * blockDim.x + threadIdx.x; i < E; i += gridDim.x * blockDim.x){
    int d = ei[E + i];
    rank[i] = atomicAdd(&cnt[d], 1);
  }
}

// one-dispatch offsets: wave shfl-scan + global cursor.
__global__ void k_offsets(const int* __restrict__ cnt, int* __restrict__ rs,
                          int* __restrict__ cursor, int Nn){
  int n = blockIdx.x * 256 + threadIdx.x;
  int lane = threadIdx.x & 63;
  int v = (n < Nn) ? cnt[n] : 0;
  int inc = v;
#pragma unroll
  for (int off = 1; off < 64; off <<= 1){
    int t = __shfl_up(inc, off);
    if (lane >= off) inc += t;
  }
  int total = __shfl(inc, 63);
  int base = 0;
  if (lane == 0) base = atomicAdd(cursor, total);
  base = __shfl(base, 0);
  if (n < Nn) rs[n] = base + inc - v;
}

__global__ void k_scatter(const int* __restrict__ ei, int E, const int* __restrict__ rs,
                          const int* __restrict__ rank, int* __restrict__ esrc){
  for (int i = blockIdx.x * blockDim.x + threadIdx.x; i < E; i += gridDim.x * blockDim.x){
    esrc[rs[ei[E + i]] + rank[i]] = ei[i];
  }
}

// ---------------- LDS-pipelined MFMA GEMM (layer-1) ----------------
// PERM: store fp8-e4m3 into pi8 layout, row stride PSTR.
template<int K, bool PERM>
__global__ __launch_bounds__(256, 2) void k_mgemm(const unsigned short* __restrict__ A,
                                                  const unsigned short* __restrict__ BT,
                                                  const float* __restrict__ bias,
                                                  unsigned short* __restrict__ C,
                                                  const float* __restrict__ a_s,
                                                  const float* __restrict__ a_d,
                                                  float* __restrict__ als, float* __restrict__ ald,
                                                  int M, int Ncols, int act){
  __shared__ unsigned short sA[2][8192];   // [buf][128 rows x 64 k] swizzled
  __shared__ unsigned short sB[2][8192];
  const int lane = threadIdx.x & 63;
  const int wave = threadIdx.x >> 6;
  const int brow = blockIdx.x * 128;
  const int bcol = blockIdx.y * 128;
  const int wr = wave >> 1, wc = wave & 1;
  const int r15 = lane & 15;
  const int kg = (lane >> 4) * 8;
  const int row0 = brow + wr * 64;
  const int col0 = bcol + wc * 64;
  f32x4 acc[4][4] = {};

  const int cbase = wave * 64 + lane;
  auto stage = [&](int buf, int kt){
#pragma unroll
    for (int j = 0; j < 4; ++j){
      int c = cbase + j * 256;
      int r = c >> 3;
      int k0 = ((c ^ r) & 7) * 8;
      int ldsoff = (wave * 64 + j * 256) * 8;   // wave-uniform; HW adds lane*16B
      int ra = brow + r; if (ra >= M) ra = M - 1;
      gload16(&A[(size_t)ra * K + kt + k0], &sA[buf][ldsoff]);
      gload16(&BT[(size_t)(bcol + r) * K + kt + k0], &sB[buf][ldsoff]);
    }
  };
  auto compute = [&](int buf){
#pragma unroll
    for (int ks = 0; ks < 2; ++ks){
      bf16x8 a[4], b[4];
#pragma unroll
      for (int m = 0; m < 4; ++m){
        int row = wr * 64 + m * 16 + r15;
        int idx = (row * 64 + ks * 32 + kg) ^ ((row & 7) << 3);
        a[m] = *reinterpret_cast<const bf16x8*>(&sA[buf][idx]);
      }
#pragma unroll
      for (int n = 0; n < 4; ++n){
        int row = wc * 64 + n * 16 + r15;
        int idx = (row * 64 + ks * 32 + kg) ^ ((row & 7) << 3);
        b[n] = *reinterpret_cast<const bf16x8*>(&sB[buf][idx]);
      }
#pragma unroll
      for (int m = 0; m < 4; ++m)
#pragma unroll
        for (int n = 0; n < 4; ++n)
          acc[m][n] = __builtin_amdgcn_mfma_f32_16x16x32_bf16(a[m], b[n], acc[m][n], 0, 0, 0);
    }
  };

  constexpr int NK = K / 64;
  stage(0, 0);
  int cur = 0;
#pragma unroll
  for (int t = 0; t < NK; ++t){
    __syncthreads();
    if (t + 1 < NK) stage(cur ^ 1, (t + 1) * 64);
    compute(cur);
    cur ^= 1;
  }

#pragma unroll
  for (int m = 0; m < 4; ++m){
#pragma unroll
    for (int n = 0; n < 4; ++n){
      int c = col0 + n * 16 + r15;
      float bsv = bias ? bias[c] : 0.f;
#pragma unroll
      for (int q = 0; q < 4; ++q){
        int r = row0 + m * 16 + (lane >> 4) * 4 + q;
        if (r < M){
          float v = acc[m][n][q] + bsv;
          if (act) v = (v > 0.f) ? v : expm1f(v);
          if (PERM) reinterpret_cast<unsigned char*>(C)[(size_t)r * PSTR + pi8(c)] = f2fp8(v);
          else C[(size_t)r * Ncols + c] = f2b(v);
        }
      }
    }
  }
  if (a_s){
    __syncthreads();
    float* sred = reinterpret_cast<float*>(&sA[0][0]);   // [2][128]
    float* dred = sred + 256;
    const int head = blockIdx.y;
    const int cin = wc * 64;
    float asv[4], adv[4];
#pragma unroll
    for (int n = 0; n < 4; ++n){
      int c = head * EMB + cin + n * 16 + r15;
      asv[n] = a_s[c]; adv[n] = a_d[c];
    }
#pragma unroll
    for (int m = 0; m < 4; ++m){
#pragma unroll
      for (int q = 0; q < 4; ++q){
        float ps = acc[m][0][q] * asv[0] + acc[m][1][q] * asv[1]
                 + acc[m][2][q] * asv[2] + acc[m][3][q] * asv[3];
        float pd = acc[m][0][q] * adv[0] + acc[m][1][q] * adv[1]
                 + acc[m][2][q] * adv[2] + acc[m][3][q] * adv[3];
#pragma unroll
        for (int off = 1; off < 16; off <<= 1){
          ps += __shfl_xor(ps, off);
          pd += __shfl_xor(pd, off);
        }
        if (r15 == 0){
          int rowl = wr * 64 + m * 16 + (lane >> 4) * 4 + q;
          sred[wc * 128 + rowl] = ps;
          dred[wc * 128 + rowl] = pd;
        }
      }
    }
    __syncthreads();
    if (threadIdx.x < 128){
      int rowl = threadIdx.x;
      int r = brow + rowl;
      if (r < M){
        als[(size_t)r * 3 + head] = sred[rowl] + sred[128 + rowl];
        ald[(size_t)r * 3 + head] = dred[rowl] + dred[128 + rowl];
      }
    }
  }
}

// ---------------- fused dependent GEMM ----------------
// T = A@B1^T + bias1 (K=384, LDS dbuf); then per 128-col chunk C = T@B2_chunk^T.
// NCH==3: fp8-pi8 store + als/ald epilogue. FINAL: dot with w2 -> sigmoid out.
template<int NCH, bool FINAL>
__global__ __launch_bounds__(256, 2) void k_fused(const unsigned short* __restrict__ A,
                                                  const unsigned short* __restrict__ B1,
                                                  const float* __restrict__ bias1,
                                                  const unsigned short* __restrict__ B2,
                                                  const float* __restrict__ bias2,
                                                  unsigned short* __restrict__ C,
                                                  const float* __restrict__ a_s,
                                                  const float* __restrict__ a_d,
                                                  float* __restrict__ als, float* __restrict__ ald,
                                                  const float* __restrict__ w2,
                                                  const float* __restrict__ b2s,
                                                  float* __restrict__ outp,
                                                  int M, int act2){
  __shared__ unsigned short sA[2][8192];   // stage-1 A dbuf; then T[128][128] swizzled
  __shared__ unsigned short sB[2][8192];   // stage-1 B dbuf; then B2 chunk (32KB)
  __shared__ float sred[2][128];
  __shared__ float dred[2][128];
  __shared__ float zsum[2][128];
  const int lane = threadIdx.x & 63;
  const int wave = threadIdx.x >> 6;
  const int brow = blockIdx.x * 128;
  const int wr = wave >> 1, wc = wave & 1;
  const int r15 = lane & 15;
  const int kg = (lane >> 4) * 8;
  const int qrow = (lane >> 4) * 4;
  f32x4 acc[4][4] = {};
  const int cbase = wave * 64 + lane;
  unsigned short* Bs = &sB[0][0];

  if (FINAL && threadIdx.x < 128){ zsum[0][threadIdx.x] = 0.f; zsum[1][threadIdx.x] = 0.f; }

  auto stageB2 = [&](int cc, int jlo, int jhi){
    for (int j = jlo; j < jhi; ++j){
      int c = cbase + j * 256;     // 128 rows x 16 chunks (CPR=16)
      int r = c >> 4;
      int cr = c & 15;
      int k0 = ((cr & 8) | ((cr ^ r) & 7)) * 8;
      int ldsoff = (wave * 64 + j * 256) * 8;
      gload16(&B2[(size_t)(cc * 128 + r) * 128 + k0], &Bs[ldsoff]);
    }
  };

  // ---- stage 1: T = A(pi)@B1^T, K=384, BK=64 double-buffered ----
  auto stage1 = [&](int buf, int kt){
#pragma unroll
    for (int j = 0; j < 4; ++j){
      int c = cbase + j * 256;
      int r = c >> 3;
      int k0 = ((c ^ r) & 7) * 8;
      int ldsoff = (wave * 64 + j * 256) * 8;
      int ra = brow + r; if (ra >= M) ra = M - 1;
      gload16(&A[(size_t)ra * HE + kt + k0], &sA[buf][ldsoff]);
      gload16(&B1[(size_t)r * HE + kt + k0], &sB[buf][ldsoff]);
    }
  };
  stage1(0, 0);
  int cur = 0;
#pragma unroll
  for (int t = 0; t < 6; ++t){
    __syncthreads();
    if (t + 1 < 6) stage1(cur ^ 1, (t + 1) * 64);
    else stageB2(0, 0, 4);   // rows 0-63 of chunk0 -> sB[0] (dead this step)
#pragma unroll
    for (int ks = 0; ks < 2; ++ks){
      bf16x8 a[4], b[4];
#pragma unroll
      for (int m = 0; m < 4; ++m){
        int row = wr * 64 + m * 16 + r15;
        int idx = (row * 64 + ks * 32 + kg) ^ ((row & 7) << 3);
        a[m] = *reinterpret_cast<const bf16x8*>(&sA[cur][idx]);
      }
#pragma unroll
      for (int n = 0; n < 4; ++n){
        int row = wc * 64 + n * 16 + r15;
        int idx = (row * 64 + ks * 32 + kg) ^ ((row & 7) << 3);
        b[n] = *reinterpret_cast<const bf16x8*>(&sB[cur][idx]);
      }
#pragma unroll
      for (int m = 0; m < 4; ++m)
#pragma unroll
        for (int n = 0; n < 4; ++n)
          acc[m][n] = __builtin_amdgcn_mfma_f32_16x16x32_bf16(a[m], b[n], acc[m][n], 0, 0, 0);
    }
    cur ^= 1;
  }
  __syncthreads();   // all stage-1 LDS reads done (+ chunk0 first-half landed)
  unsigned short* T = &sA[0][0];
#pragma unroll
  for (int m = 0; m < 4; ++m){
#pragma unroll
    for (int n = 0; n < 4; ++n){
      int col = wc * 64 + n * 16 + r15;
      float bv = bias1[col];
#pragma unroll
      for (int q = 0; q < 4; ++q){
        int row = wr * 64 + m * 16 + qrow + q;
        T[(row * 128 + col) ^ ((row & 7) << 3)] = f2b(acc[m][n][q] + bv);
      }
    }
  }

  // ---- stage 2: per 128-col chunk ----
#pragma unroll
  for (int cc = 0; cc < NCH; ++cc){
    if (cc == 0){
      __syncthreads();           // T visible; stage-1 sB[1] reads done
      stageB2(0, 4, 8);          // rows 64-127 of chunk0 -> sB[1]
    } else {
      __syncthreads();           // prev chunk's Bs reads done
      stageB2(cc, 0, 8);
    }
    __syncthreads();             // staged chunk visible
#pragma unroll
    for (int m = 0; m < 4; ++m)
#pragma unroll
      for (int n = 0; n < 4; ++n)
        acc[m][n] = (f32x4){0.f, 0.f, 0.f, 0.f};
#pragma unroll
    for (int ks = 0; ks < 4; ++ks){
      bf16x8 a[4], b[4];
#pragma unroll
      for (int m = 0; m < 4; ++m){
        int row = wr * 64 + m * 16 + r15;
        int idx = (row * 128 + ks * 32 + kg) ^ ((row & 7) << 3);
        a[m] = *reinterpret_cast<const bf16x8*>(&T[idx]);
      }
#pragma unroll
      for (int n = 0; n < 4; ++n){
        int row = wc * 64 + n * 16 + r15;
        int idx = (row * 128 + ks * 32 + kg) ^ ((row & 7) << 3);
        b[n] = *reinterpret_cast<const bf16x8*>(&Bs[idx]);
      }
#pragma unroll
      for (int m = 0; m < 4; ++m)
#pragma unroll
        for (int n = 0; n < 4; ++n)
          acc[m][n] = __builtin_amdgcn_mfma_f32_16x16x32_bf16(a[m], b[n], acc[m][n], 0, 0, 0);
    }
    if (FINAL){
      float w2v[4];
#pragma unroll
      for (int n = 0; n < 4; ++n)
        w2v[n] = w2[cc * 128 + wc * 64 + n * 16 + r15];
#pragma unroll
      for (int m = 0; m < 4; ++m){
#pragma unroll
        for (int q = 0; q < 4; ++q){
          float p = 0.f;
#pragma unroll
          for (int n = 0; n < 4; ++n){
            float v = acc[m][n][q] + bias2[cc * 128 + wc * 64 + n * 16 + r15];
            v = (v > 0.f) ? v : expm1f(v);
            p += v * w2v[n];
          }
#pragma unroll
          for (int off = 1; off < 16; off <<= 1) p += __shfl_xor(p, off);
          if (r15 == 0) zsum[wc][wr * 64 + m * 16 + qrow + q] += p;
        }
      }
    } else {
#pragma unroll
      for (int m = 0; m < 4; ++m){
#pragma unroll
        for (int n = 0; n < 4; ++n){
          int cglob = cc * 128 + wc * 64 + n * 16 + r15;
          float bv = bias2 ? bias2[cglob] : 0.f;
#pragma unroll
          for (int q = 0; q < 4; ++q){
            int rg = brow + wr * 64 + m * 16 + qrow + q;
            if (rg < M){
              float v = acc[m][n][q] + bv;
              if (act2) v = (v > 0.f) ? v : expm1f(v);
              if (NCH == 3)
                reinterpret_cast<unsigned char*>(C)[(size_t)rg * PSTR + pi8(cglob)] = f2fp8(v);
              else
                C[(size_t)rg * 512 + cglob] = f2b(v);
            }
          }
        }
      }
    }
    if (a_s){
      const int cin = wc * 64;
      float asv[4], adv[4];
#pragma unroll
      for (int n = 0; n < 4; ++n){
        int cglob = cc * 128 + cin + n * 16 + r15;
        asv[n] = a_s[cglob]; adv[n] = a_d[cglob];
      }
#pragma unroll
      for (int m = 0; m < 4; ++m){
#pragma unroll
        for (int q = 0; q < 4; ++q){
          float ps = acc[m][0][q] * asv[0] + acc[m][1][q] * asv[1]
                   + acc[m][2][q] * asv[2] + acc[m][3][q] * asv[3];
          float pd = acc[m][0][q] * adv[0] + acc[m][1][q] * adv[1]
                   + acc[m][2][q] * adv[2] + acc[m][3][q] * adv[3];
#pragma unroll
          for (int off = 1; off < 16; off <<= 1){
            ps += __shfl_xor(ps, off);
            pd += __shfl_xor(pd, off);
          }
          if (r15 == 0){
            int rowl = wr * 64 + m * 16 + qrow + q;
            sred[wc][rowl] = ps;
            dred[wc][rowl] = pd;
          }
        }
      }
      __syncthreads();
      if (threadIdx.x < 128){
        int rowl = threadIdx.x;
        int rg = brow + rowl;
        if (rg < M){
          als[(size_t)rg * 3 + cc] = sred[0][rowl] + sred[1][rowl];
          ald[(size_t)rg * 3 + cc] = dred[0][rowl] + dred[1][rowl];
        }
      }
    }
  }
  if (FINAL){
    __syncthreads();
    if (threadIdx.x < 128){
      int rg = brow + threadIdx.x;
      if (rg < M){
        float z = zsum[0][threadIdx.x] + zsum[1][threadIdx.x] + b2s[0];
        outp[rg] = 1.f / (1.f + __expf(-z));
      }
    }
  }
}

// ---------------- GAT aggregation (1 wave/node, NO LDS) + inline self-loop ----
// pass A keeps first-64-edge esrc + ex in registers; pass B reads via __shfl.
// deg>64 tail recomputes inline (not taken on this graph: max deg ~45).
__global__ __launch_bounds__(256) void k_agg(const unsigned char* __restrict__ h,
                                             const float* __restrict__ als,
                                             const float* __restrict__ ald,
                                             const int* __restrict__ rs, const int* __restrict__ cntp,
                                             const int* __restrict__ esrc,
                                             const float* __restrict__ bias,
                                             unsigned short* __restrict__ out, int Nn){
  int wave = threadIdx.x >> 6;
  int n = blockIdx.x * 4 + wave;
  int lane = threadIdx.x & 63;
  if (n >= Nn) return;
  int start = rs[n];
  int end = start + cntp[n];
  f32x3 adn = *reinterpret_cast<const f32x3*>(&ald[(size_t)n * 3]);
  f32x3 asn = *reinterpret_cast<const f32x3*>(&als[(size_t)n * 3]);
  float es0 = __expf(lrelu(asn.x + adn.x));   // self-loop term (wave-uniform)
  float es1 = __expf(lrelu(asn.y + adn.y));
  float es2 = __expf(lrelu(asn.z + adn.z));
  // pass A: lane-parallel ex + denominators; first 64 edges kept in registers
  float d0 = 0.f, d1 = 0.f, d2 = 0.f;
  int   sreg = 0;
  float e0r = 0.f, e1r = 0.f, e2r = 0.f;
  for (int i = start + lane; i < end; i += 64){
    int s = esrc[i];
    f32x3 as = *reinterpret_cast<const f32x3*>(&als[(size_t)s * 3]);
    float e0 = __expf(lrelu(as.x + adn.x));
    float e1 = __expf(lrelu(as.y + adn.y));
    float e2 = __expf(lrelu(as.z + adn.z));
    d0 += e0; d1 += e1; d2 += e2;
    if (i - start < 64){ sreg = s; e0r = e0; e1r = e1; e2r = e2; }
  }
  for (int off = 32; off; off >>= 1){
    d0 += __shfl_xor(d0, off);
    d1 += __shfl_xor(d1, off);
    d2 += __shfl_xor(d2, off);
  }
  d0 += es0; d1 += es1; d2 += es2;
  float iv[3] = {1.f / (d0 + 1e-16f), 1.f / (d1 + 1e-16f), 1.f / (d2 + 1e-16f)};
  const int l8 = lane * 8;
  float acc[6];
  {
    uint2 v = *reinterpret_cast<const uint2*>(h + (size_t)n * PSTR + l8);
    f32x2 p0 = fp8pk<false>(v.x);
    f32x2 p1 = fp8pk<true>(v.x);
    f32x2 p2 = fp8pk<false>(v.y);
    acc[0] = es0 * p0[0]; acc[1] = es0 * p0[1];
    acc[2] = es1 * p1[0]; acc[3] = es1 * p1[1];
    acc[4] = es2 * p2[0]; acc[5] = es2 * p2[1];
  }
  // pass B over register-resident edges (deg<=64 covers all on this graph)
  const int deg = end - start;
  const int nreg = (deg < 64) ? deg : 64;
  int j = 0;
  for (; j + 3 < nreg; j += 4){
    uint2 hv[4]; f32x3 ev[4];
#pragma unroll
    for (int u = 0; u < 4; ++u){
      int s = __shfl(sreg, j + u);
      hv[u] = *reinterpret_cast<const uint2*>(h + (size_t)s * PSTR + l8);
      ev[u].x = __shfl(e0r, j + u);
      ev[u].y = __shfl(e1r, j + u);
      ev[u].z = __shfl(e2r, j + u);
    }
#pragma unroll
    for (int u = 0; u < 4; ++u){
      f32x2 p0 = fp8pk<false>(hv[u].x);
      f32x2 p1 = fp8pk<true>(hv[u].x);
      f32x2 p2 = fp8pk<false>(hv[u].y);
      acc[0] += ev[u].x * p0[0]; acc[1] += ev[u].x * p0[1];
      acc[2] += ev[u].y * p1[0]; acc[3] += ev[u].y * p1[1];
      acc[4] += ev[u].z * p2[0]; acc[5] += ev[u].z * p2[1];
    }
  }
  for (; j < nreg; ++j){
    int s = __shfl(sreg, j);
    float e0 = __shfl(e0r, j), e1 = __shfl(e1r, j), e2 = __shfl(e2r, j);
    uint2 v = *reinterpret_cast<const uint2*>(h + (size_t)s * PSTR + l8);
    f32x2 p0 = fp8pk<false>(v.x);
    f32x2 p1 = fp8pk<true>(v.x);
    f32x2 p2 = fp8pk<false>(v.y);
    acc[0] += e0 * p0[0]; acc[1] += e0 * p0[1];
    acc[2] += e1 * p1[0]; acc[3] += e1 * p1[1];
    acc[4] += e2 * p2[0]; acc[5] += e2 * p2[1];
  }
  for (int i = start + 64; i < end; ++i){   // rare tail: deg>64
    int s = esrc[i];
    f32x3 as = *reinterpret_cast<const f32x3*>(&als[(size_t)s * 3]);
    float e0 = __expf(lrelu(as.x + adn.x));
    float e1 = __expf(lrelu(as.y + adn.y));
    float e2 = __expf(lrelu(as.z + adn.z));
    uint2 v = *reinterpret_cast<const uint2*>(h + (size_t)s * PSTR + l8);
    f32x2 p0 = fp8pk<false>(v.x);
    f32x2 p1 = fp8pk<true>(v.x);
    f32x2 p2 = fp8pk<false>(v.y);
    acc[0] += e0 * p0[0]; acc[1] += e0 * p0[1];
    acc[2] += e1 * p1[0]; acc[3] += e1 * p1[1];
    acc[4] += e2 * p2[0]; acc[5] += e2 * p2[1];
  }
  unsigned ov[3];
#pragma unroll
  for (int hh = 0; hh < 3; ++hh){
    int ch = 128 * hh + 2 * lane;
    float v0 = acc[2 * hh] * iv[hh] + bias[ch];
    float v1 = acc[2 * hh + 1] * iv[hh] + bias[ch + 1];
    v0 = (v0 > 0.f) ? v0 : expm1f(v0);
    v1 = (v1 > 0.f) ? v1 : expm1f(v1);
    ov[hh] = (unsigned)f2b(v0) | ((unsigned)f2b(v1) << 16);
  }
  // Q stays bf16 pi layout: lane's 3 dwords at dword offset lane*3
  unsigned* orow = reinterpret_cast<unsigned*>(out + (size_t)n * HE) + lane * 3;
  orow[0] = ov[0]; orow[1] = ov[1]; orow[2] = ov[2];
}

extern "C" void kernel_launch(void* const* d_in, const int* in_sizes, int n_in,
                              void* d_out, int out_size, void* d_ws, size_t ws_size,
                              hipStream_t stream){
  const float* x   = (const float*)d_in[0];
  const int*   ei  = (const int*)d_in[1];
  const int N = in_sizes[0] / F_IN;
  const int E = in_sizes[1] / 2;
  const float* W[3]  = {(const float*)d_in[2], (const float*)d_in[6], (const float*)d_in[10]};
  const float* AS[3] = {(const float*)d_in[3], (const float*)d_in[7], (const float*)d_in[11]};
  const float* AD[3] = {(const float*)d_in[4], (const float*)d_in[8], (const float*)d_in[12]};
  const float* BB[3] = {(const float*)d_in[5], (const float*)d_in[9], (const float*)d_in[13]};
  const float* WH[3] = {(const float*)d_in[14], (const float*)d_in[16], (const float*)d_in[18]};
  const float* BH[3] = {(const float*)d_in[15], (const float*)d_in[17], (const float*)d_in[19]};
  const float* Wl1 = (const float*)d_in[20];
  const float* bl1 = (const float*)d_in[21];
  const float* Wl2 = (const float*)d_in[22];
  const float* bl2 = (const float*)d_in[23];
  float* out = (float*)d_out;

  // ---- workspace layout ----
  char* ws = (char*)d_ws;
  size_t off = 0;
  auto alloc = [&](size_t bytes) -> char* {
    char* p = ws + off;
    off = (off + bytes + 255) & ~(size_t)255;
    return p;
  };
  int*   row_start = (int*)alloc((size_t)N * 4);
  int*   cnt       = (int*)alloc((size_t)N * 4);
  int*   esrc      = (int*)alloc((size_t)E * 4);
  int*   rank      = (int*)alloc((size_t)E * 4);
  int*   cursor    = (int*)alloc(256);
  float* als       = (float*)alloc((size_t)N * 3 * 4);
  float* ald       = (float*)alloc((size_t)N * 3 * 4);
  unsigned short* xb = (unsigned short*)alloc((size_t)N * F_IN * 2);   // x bf16
  unsigned char*  P  = (unsigned char*)alloc((size_t)N * PSTR);        // h fp8 (pi8, stride 512)
  unsigned short* Q  = (unsigned short*)alloc((size_t)N * HE * 2);     // agg out bf16 (pi layout)
  // weight slabs
  unsigned short* W1T  = (unsigned short*)alloc((size_t)F_IN * HE * 2);  // [384,128]
  unsigned short* W2T  = (unsigned short*)alloc((size_t)F_IN * HE * 2);
  unsigned short* W3T  = (unsigned short*)alloc((size_t)F_IN * HE * 2);
  unsigned short* WhPT[3];
  for (int l = 0; l < 3; ++l)
    WhPT[l] = (unsigned short*)alloc((size_t)HE * F_IN * 2);            // [128,384] K pi-permuted
  unsigned short* Wl1T = (unsigned short*)alloc((size_t)F_IN * 512 * 2); // [512,128]

  // ---- single prep dispatch ----
  const int n4 = N * F_IN / 4;
  const int prep_total = n4 + 6 * S1 + S3 + N + 1;
  k_prep<<<(prep_total + 255) / 256, 256, 0, stream>>>(
      x, xb, n4, W[0], W[1], W[2], W1T, W2T, W3T,
      WH[0], WH[1], WH[2], WhPT[0], WhPT[1], WhPT[2], Wl1, Wl1T, cnt, cursor, N);

  // ---- CSR by dst ----
  k_hist<<<2048, 256, 0, stream>>>(ei, E, cnt, rank);
  k_offsets<<<(N + 255) / 256, 256, 0, stream>>>(cnt, row_start, cursor, N);
  k_scatter<<<2048, 256, 0, stream>>>(ei, E, row_start, rank, esrc);

  const int mb = (N + 127) / 128;
  const int nwave = (N + 3) / 4;

  // ---- layer 1: P(fp8) = x@W1 + als/ald; agg ----
  k_mgemm<128, true><<<dim3(mb, 3), 256, 0, stream>>>(xb, W1T, nullptr,
      (unsigned short*)P, AS[0], AD[0], als, ald, N, HE, 0);
  k_agg<<<nwave, 256, 0, stream>>>(P, als, ald, row_start, cnt, esrc, BB[0], Q, N);
  // ---- layer 2: fused (R1 = Q@Wh1+bh1) -> P(fp8) = R1@W2 + als/ald; agg ----
  k_fused<3, false><<<mb, 256, 0, stream>>>(Q, WhPT[0], BH[0], W2T, nullptr,
      (unsigned short*)P, AS[1], AD[1], als, ald, nullptr, nullptr, nullptr, N, 0);
  k_agg<<<nwave, 256, 0, stream>>>(P, als, ald, row_start, cnt, esrc, BB[1], Q, N);
  // ---- layer 3 ----
  k_fused<3, false><<<mb, 256, 0, stream>>>(Q, WhPT[1], BH[1], W3T, nullptr,
      (unsigned short*)P, AS[2], AD[2], als, ald, nullptr, nullptr, nullptr, N, 0);
  k_agg<<<nwave, 256, 0, stream>>>(P, als, ald, row_start, cnt, esrc, BB[2], Q, N);
  // ---- MLP + head fused ----
  k_fused<4, true><<<mb, 256, 0, stream>>>(Q, WhPT[2], BH[2], Wl1T, bl1, nullptr,
      nullptr, nullptr, nullptr, nullptr, Wl2, bl2, out, N, 1);
}